// Round 10
// baseline (321.563 us; speedup 1.0000x reference)
//
#include <hip/hip_runtime.h>

#define NN 100000
#define ENUM 25000
#define NNZ_C 200000
// D = 128, H = 4, F = 128, Wlin: [128,512]
// Xlin layout: [row][f][h] via row-permuted Wcomb rows. ax/ae folded into producers.

typedef __attribute__((ext_vector_type(8))) short bf16x8;
typedef __attribute__((ext_vector_type(4))) float f32x4;

__device__ __forceinline__ float bf2f(unsigned short v) {
    return __uint_as_float(((unsigned)v) << 16);
}
__device__ __forceinline__ float blo(unsigned u) { return __uint_as_float(u << 16); }
__device__ __forceinline__ float bhi(unsigned u) { return __uint_as_float(u & 0xFFFF0000u); }
__device__ __forceinline__ unsigned short f2bf(float x) {
    unsigned u = __float_as_uint(x);
    unsigned r = (u + 0x7fff + ((u >> 16) & 1)) >> 16;   // RNE
    return (unsigned short)r;
}
__device__ __forceinline__ unsigned pack2(float a, float b) {
    return (unsigned)f2bf(a) | ((unsigned)f2bf(b) << 16);
}

// -------- W[128][NC] f32 -> Wt[cc][128] bf16; PERM: cc=(c&127)*4+(c>>7) --------
template <bool PERM>
__global__ __launch_bounds__(256) void wtr_k(
    const float* __restrict__ W, unsigned short* __restrict__ Wt, int NC)
{
    const int t = blockIdx.x * 256 + threadIdx.x;
    if (t >= 128 * NC) return;
    const int c = t % NC, k = t / NC;
    const int cc = PERM ? ((c & 127) * 4 + (c >> 7)) : c;
    Wt[cc * 128 + k] = f2bf(W[t]);
}

// -------- A1/A2[k][h] = sum_f Wlin[k][h*128+f] * att[h*256 + (pair?128:0) + f] ----
__global__ __launch_bounds__(256) void attw_k(
    const float* __restrict__ Wlin, const float* __restrict__ att,
    float* __restrict__ A1, float* __restrict__ A2)
{
    const int t = threadIdx.x;
    const int k = t & 127;
    const int pair = t >> 7;
    const float* wrow = Wlin + (size_t)k * 512;
    float s[4];
    #pragma unroll
    for (int h = 0; h < 4; h++) {
        float acc = 0.f;
        const float* ap = att + h * 256 + pair * 128;
        const float* wp = wrow + h * 128;
        for (int f = 0; f < 128; f++) acc += wp[f] * ap[f];
        s[h] = acc;
    }
    float* dst = (pair ? A2 : A1) + k * 4;
    dst[0] = s[0]; dst[1] = s[1]; dst[2] = s[2]; dst[3] = s[3];
}

// ---- fused X GEMM: Xt = bf16(X@Wn+bn), Xlin = bf16(X@Wlin permuted), ax = X@A1 ----
// Wc: [640][128] bf16 (rows 0-127: WnT; 128-639: permuted WlinT)
__global__ __launch_bounds__(256) void gemmx_k(
    const float* __restrict__ X, const unsigned short* __restrict__ Wc,
    const float* __restrict__ bn, const float* __restrict__ A1,
    unsigned short* __restrict__ Xt, unsigned short* __restrict__ Xlin,
    float* __restrict__ ax, int M)
{
    __shared__ unsigned short As[64 * 128];
    __shared__ unsigned short Bs[64 * 128];
    __shared__ float A1s[512];
    const int tid = threadIdx.x;
    const int r0 = blockIdx.x * 64;

    // stage A (f32 -> bf16, swizzled)
    {
        int rr = tid >> 4;
        const int kc = (tid & 15) * 8;
        #pragma unroll
        for (int it = 0; it < 4; it++) {
            int r = r0 + rr; if (r > M - 1) r = M - 1;
            const float* ap = X + (size_t)r * 128 + kc;
            const float4 f0 = *(const float4*)ap;
            const float4 f1 = *(const float4*)(ap + 4);
            uint4 va;
            va.x = pack2(f0.x, f0.y); va.y = pack2(f0.z, f0.w);
            va.z = pack2(f1.x, f1.y); va.w = pack2(f1.z, f1.w);
            *(uint4*)&As[(rr * 128 + kc) ^ ((rr & 7) << 3)] = va;
            rr += 16;
        }
    }
    A1s[tid] = A1[tid];
    A1s[tid + 256] = A1[tid + 256];
    __syncthreads();

    const int lane = tid & 63;
    const int wid = tid >> 6;
    const int wr = wid >> 1, wc = wid & 1;
    const int fr = lane & 15;
    const int kg = (lane >> 4) * 8;

    // hoist A fragments (ALL indices compile-time -> stays in registers; rule #20)
    bf16x8 a[2][4];
    #pragma unroll
    for (int m = 0; m < 2; m++) {
        const int ar = wr * 32 + m * 16 + fr;
        #pragma unroll
        for (int ks = 0; ks < 4; ks++)
            a[m][ks] = *(const bf16x8*)&As[(ar * 128 + ks * 32 + kg) ^ ((ar & 7) << 3)];
    }

    for (int ct = 0; ct < 10; ct++) {
        __syncthreads();   // prior Bs reads complete
        {
            int rr = tid >> 4;
            const int kc = (tid & 15) * 8;
            #pragma unroll
            for (int it = 0; it < 4; it++) {
                const uint4 vb = *(const uint4*)(Wc + (size_t)(ct * 64 + rr) * 128 + kc);
                *(uint4*)&Bs[(rr * 128 + kc) ^ ((rr & 7) << 3)] = vb;
                rr += 16;
            }
        }
        __syncthreads();

        f32x4 acc[2][2] = {};
        #pragma unroll
        for (int ks = 0; ks < 4; ks++) {
            bf16x8 b[2];
            #pragma unroll
            for (int n = 0; n < 2; n++) {
                const int br = wc * 32 + n * 16 + fr;
                b[n] = *(const bf16x8*)&Bs[(br * 128 + ks * 32 + kg) ^ ((br & 7) << 3)];
            }
            #pragma unroll
            for (int m = 0; m < 2; m++)
                #pragma unroll
                for (int n = 0; n < 2; n++)
                    acc[m][n] = __builtin_amdgcn_mfma_f32_16x16x32_bf16(a[m][ks], b[n], acc[m][n], 0, 0, 0);
        }

        #pragma unroll
        for (int m = 0; m < 2; m++) {
            #pragma unroll
            for (int n = 0; n < 2; n++) {
                const int ccol = wc * 32 + n * 16 + fr;
                #pragma unroll
                for (int j = 0; j < 4; j++) {
                    const int r = r0 + wr * 32 + m * 16 + (lane >> 4) * 4 + j;
                    if (r < M) {
                        const float v = acc[m][n][j];
                        if (ct < 2) {
                            const int c = ct * 64 + ccol;
                            Xt[(size_t)r * 128 + c] = f2bf(v + bn[c]);
                        } else {
                            const int c = (ct - 2) * 64 + ccol;
                            Xlin[(size_t)r * 512 + c] = f2bf(v);
                        }
                    }
                }
            }
        }
    }

    // ---- ax epilogue: STATIC indexing into a[][] (wc is runtime -> branch, not index) ----
    {
        float s0 = 0.f, s1 = 0.f, s2 = 0.f, s3 = 0.f;
        #pragma unroll
        for (int ks = 0; ks < 4; ks++) {
            bf16x8 fa;
            if (wc == 0) fa = a[0][ks]; else fa = a[1][ks];
            #pragma unroll
            for (int i = 0; i < 8; i++) {
                const float xv = bf2f((unsigned short)fa[i]);
                const float* ap = A1s + (ks * 32 + kg + i) * 4;
                s0 += xv * ap[0]; s1 += xv * ap[1];
                s2 += xv * ap[2]; s3 += xv * ap[3];
            }
        }
        s0 += __shfl_xor(s0, 16); s1 += __shfl_xor(s1, 16);
        s2 += __shfl_xor(s2, 16); s3 += __shfl_xor(s3, 16);
        s0 += __shfl_xor(s0, 32); s1 += __shfl_xor(s1, 32);
        s2 += __shfl_xor(s2, 32); s3 += __shfl_xor(s3, 32);
        const int r = r0 + wr * 32 + wc * 16 + fr;
        if ((lane >> 4) == 0 && r < M)
            *(float4*)(ax + (size_t)r * 4) = make_float4(s0, s1, s2, s3);
    }
}

// ---------------- MFMA GEMM (E path), A staged once, CT column tiles ----------------
template <bool BF16OUT, int CT, bool AF32>
__global__ __launch_bounds__(256) void gemm2_k(
    const void* __restrict__ Av, const unsigned short* __restrict__ Wt,
    const float* __restrict__ bias, const float* __restrict__ resid,
    void* __restrict__ Cv, int M)
{
    const int NC = CT * 64;
    __shared__ unsigned short As[64 * 128];
    __shared__ unsigned short Bs[64 * 128];
    const int tid = threadIdx.x;
    const int r0 = blockIdx.x * 64;

    {
        int rr = tid >> 4;
        const int kc = (tid & 15) * 8;
        #pragma unroll
        for (int it = 0; it < 4; it++) {
            int r = r0 + rr; if (r > M - 1) r = M - 1;
            uint4 va;
            if (AF32) {
                const float* ap = (const float*)Av + (size_t)r * 128 + kc;
                const float4 f0 = *(const float4*)ap;
                const float4 f1 = *(const float4*)(ap + 4);
                va.x = pack2(f0.x, f0.y); va.y = pack2(f0.z, f0.w);
                va.z = pack2(f1.x, f1.y); va.w = pack2(f1.z, f1.w);
            } else {
                va = *(const uint4*)((const unsigned short*)Av + (size_t)r * 128 + kc);
            }
            *(uint4*)&As[(rr * 128 + kc) ^ ((rr & 7) << 3)] = va;
            rr += 16;
        }
    }
    __syncthreads();

    const int lane = tid & 63;
    const int wid = tid >> 6;
    const int wr = wid >> 1, wc = wid & 1;
    const int fr = lane & 15;
    const int kg = (lane >> 4) * 8;

    bf16x8 a[2][4];
    #pragma unroll
    for (int m = 0; m < 2; m++) {
        const int ar = wr * 32 + m * 16 + fr;
        #pragma unroll
        for (int ks = 0; ks < 4; ks++)
            a[m][ks] = *(const bf16x8*)&As[(ar * 128 + ks * 32 + kg) ^ ((ar & 7) << 3)];
    }

    for (int ct = 0; ct < CT; ct++) {
        const int c0 = ct * 64;
        __syncthreads();
        {
            int rr = tid >> 4;
            const int kc = (tid & 15) * 8;
            #pragma unroll
            for (int it = 0; it < 4; it++) {
                const uint4 vb = *(const uint4*)(Wt + (size_t)(c0 + rr) * 128 + kc);
                *(uint4*)&Bs[(rr * 128 + kc) ^ ((rr & 7) << 3)] = vb;
                rr += 16;
            }
        }
        __syncthreads();

        f32x4 acc[2][2] = {};
        #pragma unroll
        for (int ks = 0; ks < 4; ks++) {
            bf16x8 b[2];
            #pragma unroll
            for (int n = 0; n < 2; n++) {
                const int br = wc * 32 + n * 16 + fr;
                b[n] = *(const bf16x8*)&Bs[(br * 128 + ks * 32 + kg) ^ ((br & 7) << 3)];
            }
            #pragma unroll
            for (int m = 0; m < 2; m++)
                #pragma unroll
                for (int n = 0; n < 2; n++)
                    acc[m][n] = __builtin_amdgcn_mfma_f32_16x16x32_bf16(a[m][ks], b[n], acc[m][n], 0, 0, 0);
        }

        #pragma unroll
        for (int m = 0; m < 2; m++) {
            #pragma unroll
            for (int n = 0; n < 2; n++) {
                const int c = c0 + wc * 32 + n * 16 + (lane & 15);
                #pragma unroll
                for (int j = 0; j < 4; j++) {
                    const int r = r0 + wr * 32 + m * 16 + (lane >> 4) * 4 + j;
                    if (r < M) {
                        float v = acc[m][n][j];
                        if (bias) v += bias[c];
                        if (resid) v += resid[(size_t)r * NC + c];
                        if (BF16OUT) ((unsigned short*)Cv)[(size_t)r * NC + c] = f2bf(v);
                        else         ((float*)Cv)[(size_t)r * NC + c] = v;
                    }
                }
            }
        }
    }
}

// ---- edge aggregation + fused ae: Eres final, ae[e,h] = Eres[e,:]·A2[:,h] ----
__global__ __launch_bounds__(256) void edge_agg_k(
    const int* __restrict__ row, const float* __restrict__ adjv,
    const unsigned short* __restrict__ Xt, const float* __restrict__ A2,
    float* __restrict__ Eres, float* __restrict__ ae)
{
    __shared__ float part[4][4];
    const int s = threadIdx.x >> 7;
    const int e = blockIdx.x * 2 + s;
    const int f = threadIdx.x & 127;
    float v = 0.f;
    if (e < ENUM) {
        float acc = 0.f, deg = 0.f;
        #pragma unroll
        for (int j = 0; j < 8; j++) {
            const int k = e + j * ENUM;
            const float w = adjv[k];
            deg += w;
            acc += w * blo(Xt[(size_t)row[k] * 128 + f]);
        }
        v = Eres[(size_t)e * 128 + f] + acc / deg;
        Eres[(size_t)e * 128 + f] = v;
    }
    const float4 a2 = *(const float4*)(A2 + f * 4);
    float p0 = v * a2.x, p1 = v * a2.y, p2 = v * a2.z, p3 = v * a2.w;
    #pragma unroll
    for (int off = 1; off < 64; off <<= 1) {
        p0 += __shfl_xor(p0, off); p1 += __shfl_xor(p1, off);
        p2 += __shfl_xor(p2, off); p3 += __shfl_xor(p3, off);
    }
    const int w = threadIdx.x >> 6;
    if ((threadIdx.x & 63) == 0) {
        part[w][0] = p0; part[w][1] = p1; part[w][2] = p2; part[w][3] = p3;
    }
    __syncthreads();
    if ((threadIdx.x & 127) == 0 && e < ENUM) {
        float4 o;
        o.x = part[2 * s][0] + part[2 * s + 1][0];
        o.y = part[2 * s][1] + part[2 * s + 1][1];
        o.z = part[2 * s][2] + part[2 * s + 1][2];
        o.w = part[2 * s][3] + part[2 * s + 1][3];
        *(float4*)(ae + (size_t)e * 4) = o;
    }
}

// -------- CSR build --------
__global__ __launch_bounds__(256) void zero_k(unsigned* __restrict__ p, int n)
{
    const int t = blockIdx.x * 256 + threadIdx.x;
    if (t < n) p[t] = 0u;
}

__global__ __launch_bounds__(256) void hist_k(
    const int* __restrict__ row, int* __restrict__ cnt)
{
    const int k = blockIdx.x * 256 + threadIdx.x;
    if (k < NNZ_C) atomicAdd(cnt + row[k], 1);
}

__global__ __launch_bounds__(256) void scan1_k(
    const int* __restrict__ cnt, int* __restrict__ rp, int* __restrict__ bsum, int n)
{
    __shared__ int sh[256];
    const int t = threadIdx.x, g = blockIdx.x * 256 + t;
    const int v = (g < n) ? cnt[g] : 0;
    sh[t] = v; __syncthreads();
    #pragma unroll
    for (int off = 1; off < 256; off <<= 1) {
        const int add = (t >= off) ? sh[t - off] : 0;
        __syncthreads();
        sh[t] += add;
        __syncthreads();
    }
    if (g < n) rp[g] = sh[t] - v;
    if (t == 255) bsum[blockIdx.x] = sh[255];
}

__global__ __launch_bounds__(512) void scan2_k(int* __restrict__ bsum, int nb)
{
    __shared__ int sh[512];
    const int t = threadIdx.x;
    const int v = (t < nb) ? bsum[t] : 0;
    sh[t] = v; __syncthreads();
    #pragma unroll
    for (int off = 1; off < 512; off <<= 1) {
        const int add = (t >= off) ? sh[t - off] : 0;
        __syncthreads();
        sh[t] += add;
        __syncthreads();
    }
    if (t < nb) bsum[t] = sh[t] - v;
}

__global__ __launch_bounds__(256) void scan3_k(
    int* __restrict__ rp, const int* __restrict__ bsum, int* __restrict__ cur, int n)
{
    const int g = blockIdx.x * 256 + threadIdx.x;
    if (g < n) {
        const int v = rp[g] + bsum[g >> 8];
        rp[g] = v;
        cur[g] = v;
    }
    if (g == 0) rp[n] = NNZ_C;
}

__global__ __launch_bounds__(256) void fill_k(
    const int* __restrict__ row, int* __restrict__ cur, int* __restrict__ eidx)
{
    const int k = blockIdx.x * 256 + threadIdx.x;
    if (k < NNZ_C) {
        const int p = atomicAdd(cur + row[k], 1);
        eidx[p] = k;
    }
}

// -------- CSR segment softmax (alpha in k-order) --------
__global__ __launch_bounds__(256) void softmax_csr_k(
    const int* __restrict__ rowptr, const int* __restrict__ eidx,
    const float* __restrict__ ax, const float* __restrict__ ae,
    float* __restrict__ alpha)
{
    const int t = blockIdx.x * 256 + threadIdx.x;
    if (t >= NN * 4) return;
    const int r = t >> 2, h = t & 3;
    const int p0 = rowptr[r], p1 = rowptr[r + 1];
    if (p0 == p1) return;
    const float axv = ax[t];
    float m = -1e30f;
    for (int p = p0; p < p1; ++p) {
        const int c = eidx[p] % ENUM;           // col[k] == k % EN by construction
        float a = axv + ae[c * 4 + h];
        a = (a >= 0.f) ? a : 0.2f * a;
        m = fmaxf(m, a);
    }
    float s = 0.f;
    for (int p = p0; p < p1; ++p) {
        const int k = eidx[p];
        const int c = k % ENUM;
        float a = axv + ae[c * 4 + h];
        a = (a >= 0.f) ? a : 0.2f * a;
        const float e = __expf(a - m);
        s += e;
        alpha[(size_t)k * 4 + h] = e;
    }
    const float rs = 1.f / s;
    for (int p = p0; p < p1; ++p)
        alpha[(size_t)eidx[p] * 4 + h] *= rs;
}

// -------- out_e[e][f][h] = (1/8) sum_j alpha[k,h] * Xlin[row[k]][f][h]  (bf16) ----
__global__ __launch_bounds__(256) void out_e_k(
    const int* __restrict__ row, const float* __restrict__ alpha,
    const unsigned short* __restrict__ Xlin, unsigned short* __restrict__ out_e)
{
    const int e = blockIdx.x * 4 + (threadIdx.x >> 6);
    const int lane = threadIdx.x & 63;
    if (e >= ENUM) return;
    const int f0 = lane * 2;
    float a0 = 0.f, a1 = 0.f, a2 = 0.f, a3 = 0.f;
    float a4 = 0.f, a5 = 0.f, a6 = 0.f, a7 = 0.f;
    #pragma unroll
    for (int j = 0; j < 8; j++) {
        const int k = e + j * ENUM;
        const int r = row[k];
        const float4 al = *(const float4*)(alpha + (size_t)k * 4);
        const uint4 u = *(const uint4*)(Xlin + (size_t)r * 512 + f0 * 4);
        a0 += al.x * blo(u.x); a1 += al.y * bhi(u.x);
        a2 += al.z * blo(u.y); a3 += al.w * bhi(u.y);
        a4 += al.x * blo(u.z); a5 += al.y * bhi(u.z);
        a6 += al.z * blo(u.w); a7 += al.w * bhi(u.w);
    }
    uint4 o;
    o.x = pack2(0.125f * a0, 0.125f * a1);
    o.y = pack2(0.125f * a2, 0.125f * a3);
    o.z = pack2(0.125f * a4, 0.125f * a5);
    o.w = pack2(0.125f * a6, 0.125f * a7);
    *(uint4*)(out_e + (size_t)e * 512 + f0 * 4) = o;
}

// -------- final CSR gather --------
__global__ __launch_bounds__(256) void xgather_k(
    const int* __restrict__ rowptr, const int* __restrict__ eidx,
    const float* __restrict__ adjv, const float* __restrict__ alpha,
    const unsigned short* __restrict__ out_e, const float* __restrict__ bias,
    float* __restrict__ Xres)
{
    const int r = blockIdx.x * 4 + (threadIdx.x >> 6);
    const int lane = threadIdx.x & 63;
    if (r >= NN) return;
    const int p0 = rowptr[r], p1 = rowptr[r + 1];
    const int f0 = lane * 2;
    float a0 = 0.f, a1 = 0.f, ds = 0.f;

#define XG_BODY(P) {                                                          \
        const int k = eidx[P];                                                \
        const int c = k % ENUM;                                               \
        ds += adjv[c];                                                        \
        const float4 al = *(const float4*)(alpha + ((size_t)k << 2));         \
        const uint4 u = *(const uint4*)(out_e + (size_t)c * 512 + f0 * 4);    \
        a0 += al.x * blo(u.x) + al.y * bhi(u.x) + al.z * blo(u.y) + al.w * bhi(u.y); \
        a1 += al.x * blo(u.z) + al.y * bhi(u.z) + al.z * blo(u.w) + al.w * bhi(u.w); \
    }

    int p = p0;
    for (; p + 2 <= p1; p += 2) { XG_BODY(p); XG_BODY(p + 1); }
    if (p < p1) XG_BODY(p);
#undef XG_BODY

    const float w = (p1 > p0) ? 0.25f / ds : 0.f;
    float2 o;
    o.x = bias[f0] + w * a0;
    o.y = bias[f0 + 1] + w * a1;
    *(float2*)(Xres + (size_t)r * 128 + f0) = o;
}

extern "C" void kernel_launch(void* const* d_in, const int* in_sizes, int n_in,
                              void* d_out, int out_size, void* d_ws, size_t ws_size,
                              hipStream_t stream)
{
    const float* X         = (const float*)d_in[0];
    const float* E         = (const float*)d_in[1];
    const int*   adj       = (const int*)d_in[2];
    const float* adjv      = (const float*)d_in[3];
    const float* Wn        = (const float*)d_in[4];
    const float* bn        = (const float*)d_in[5];
    const float* We        = (const float*)d_in[6];
    const float* be        = (const float*)d_in[7];
    const float* Wlin      = (const float*)d_in[8];
    const float* att       = (const float*)d_in[9];
    const float* bias_conv = (const float*)d_in[10];
    const int* row = adj;

    float* Xres = (float*)d_out;
    float* Eres = Xres + (size_t)NN * 128;

    // workspace layout (~161 MB)
    char* wsb = (char*)d_ws;
    unsigned short* out_e = (unsigned short*)(wsb);              // 25.6 MB
    unsigned short* Xt    = (unsigned short*)(wsb + 25600000);   // 25.6 MB
    unsigned short* Xlin  = (unsigned short*)(wsb + 51200000);   // 102.4 MB
    unsigned short* Wcomb = (unsigned short*)(wsb + 153600000);  // 160 KB ([640][128])
    unsigned short* WeT   = (unsigned short*)(wsb + 153763840);  // 32 KB
    float* A1    = (float*)(wsb + 153796608);                    // 2 KB
    float* A2    = (float*)(wsb + 153798656);                    // 2 KB
    float* ax    = (float*)(wsb + 153800704);                    // 1.6 MB
    float* ae    = (float*)(wsb + 155400704);                    // 0.4 MB
    float* alpha = (float*)(wsb + 155800704);                    // 3.2 MB
    int* rowptr  = (int*)(wsb + 159000704);                      // 400,016 B
    int* cnt     = (int*)(wsb + 159400720);                      // 400,000 B
    int* eidx    = (int*)(wsb + 159800720);                      // 800,000 B
    int* bsum    = (int*)(wsb + 160600720);                      // 2 KB

    // ---- CSR build ----
    zero_k<<<(NN + 255) / 256, 256, 0, stream>>>((unsigned*)cnt, NN);
    hist_k<<<(NNZ_C + 255) / 256, 256, 0, stream>>>(row, cnt);
    scan1_k<<<(NN + 255) / 256, 256, 0, stream>>>(cnt, rowptr, bsum, NN);
    scan2_k<<<1, 512, 0, stream>>>(bsum, (NN + 255) / 256);
    scan3_k<<<(NN + 255) / 256, 256, 0, stream>>>(rowptr, bsum, cnt, NN);
    fill_k<<<(NNZ_C + 255) / 256, 256, 0, stream>>>(row, cnt, eidx);

    // ---- weight prep ----
    wtr_k<false><<<64, 256, 0, stream>>>(Wn, Wcomb, 128);                  // rows 0-127
    wtr_k<true><<<256, 256, 0, stream>>>(Wlin, Wcomb + 128 * 128, 512);    // rows 128-639
    wtr_k<false><<<64, 256, 0, stream>>>(We, WeT, 128);
    attw_k<<<1, 256, 0, stream>>>(Wlin, att, A1, A2);

    // ---- fused X pipeline: Xt + Xlin + ax in one pass over X ----
    gemmx_k<<<1563, 256, 0, stream>>>(X, Wcomb, bn, A1, Xt, Xlin, ax, NN);

    // ---- E path ----
    gemm2_k<false, 2, true><<<391, 256, 0, stream>>>(E, WeT, be, E, Eres, ENUM);
    edge_agg_k<<<ENUM / 2, 256, 0, stream>>>(row, adjv, Xt, A2, Eres, ae);

    // ---- CSR softmax ----
    softmax_csr_k<<<(NN * 4) / 256 + 1, 256, 0, stream>>>(rowptr, eidx, ax, ae, alpha);

    // ---- node -> hyperedge ----
    out_e_k<<<ENUM / 4, 256, 0, stream>>>(row, alpha, Xlin, out_e);

    // ---- hyperedge -> node ----
    xgather_k<<<NN / 4, 256, 0, stream>>>(rowptr, eidx, adjv, alpha, out_e, bias_conv, Xres);
}

// Round 11
// 242.439 us; speedup vs baseline: 1.3264x; 1.3264x over previous
//
#include <hip/hip_runtime.h>

#define NN 100000
#define ENUM 25000
#define NNZ_C 200000
// D = 128, H = 4, F = 128, Wlin: [128,512]
// Xlin layout: [row][f][h] via row-permuted Wcomb rows. ax/ae folded into producers.

typedef __attribute__((ext_vector_type(8))) short bf16x8;
typedef __attribute__((ext_vector_type(4))) float f32x4;

__device__ __forceinline__ float bf2f(unsigned short v) {
    return __uint_as_float(((unsigned)v) << 16);
}
__device__ __forceinline__ float blo(unsigned u) { return __uint_as_float(u << 16); }
__device__ __forceinline__ float bhi(unsigned u) { return __uint_as_float(u & 0xFFFF0000u); }
__device__ __forceinline__ unsigned short f2bf(float x) {
    unsigned u = __float_as_uint(x);
    unsigned r = (u + 0x7fff + ((u >> 16) & 1)) >> 16;   // RNE
    return (unsigned short)r;
}
__device__ __forceinline__ unsigned pack2(float a, float b) {
    return (unsigned)f2bf(a) | ((unsigned)f2bf(b) << 16);
}

// -------- W[128][NC] f32 -> Wt[cc][128] bf16; PERM: cc=(c&127)*4+(c>>7) --------
template <bool PERM>
__global__ __launch_bounds__(256) void wtr_k(
    const float* __restrict__ W, unsigned short* __restrict__ Wt, int NC)
{
    const int t = blockIdx.x * 256 + threadIdx.x;
    if (t >= 128 * NC) return;
    const int c = t % NC, k = t / NC;
    const int cc = PERM ? ((c & 127) * 4 + (c >> 7)) : c;
    Wt[cc * 128 + k] = f2bf(W[t]);
}

// -------- A1/A2[k][h] = sum_f Wlin[k][h*128+f] * att[h*256 + (pair?128:0) + f] ----
__global__ __launch_bounds__(256) void attw_k(
    const float* __restrict__ Wlin, const float* __restrict__ att,
    float* __restrict__ A1, float* __restrict__ A2)
{
    const int t = threadIdx.x;
    const int k = t & 127;
    const int pair = t >> 7;
    const float* wrow = Wlin + (size_t)k * 512;
    float s[4];
    #pragma unroll
    for (int h = 0; h < 4; h++) {
        float acc = 0.f;
        const float* ap = att + h * 256 + pair * 128;
        const float* wp = wrow + h * 128;
        for (int f = 0; f < 128; f++) acc += wp[f] * ap[f];
        s[h] = acc;
    }
    float* dst = (pair ? A2 : A1) + k * 4;
    dst[0] = s[0]; dst[1] = s[1]; dst[2] = s[2]; dst[3] = s[3];
}

// ---- fused X GEMM: Xt = bf16(X@Wn+bn), Xlin = bf16(X@Wlin permuted), ax = X@A1 ----
// Wc: [640][128] bf16 (rows 0-127: WnT; 128-639: permuted WlinT)
// ax computed BEFORE the main loop, straight from LDS As (no fragment liveness
// across the loop -> no spill; rule #20 lesson from R9/R10).
__global__ __launch_bounds__(256) void gemmx_k(
    const float* __restrict__ X, const unsigned short* __restrict__ Wc,
    const float* __restrict__ bn, const float* __restrict__ A1,
    unsigned short* __restrict__ Xt, unsigned short* __restrict__ Xlin,
    float* __restrict__ ax, int M)
{
    __shared__ unsigned short As[64 * 128];
    __shared__ unsigned short Bs[64 * 128];
    __shared__ float A1s[512];
    const int tid = threadIdx.x;
    const int r0 = blockIdx.x * 64;

    // stage A (f32 -> bf16, swizzled)
    {
        int rr = tid >> 4;
        const int kc = (tid & 15) * 8;
        #pragma unroll
        for (int it = 0; it < 4; it++) {
            int r = r0 + rr; if (r > M - 1) r = M - 1;
            const float* ap = X + (size_t)r * 128 + kc;
            const float4 f0 = *(const float4*)ap;
            const float4 f1 = *(const float4*)(ap + 4);
            uint4 va;
            va.x = pack2(f0.x, f0.y); va.y = pack2(f0.z, f0.w);
            va.z = pack2(f1.x, f1.y); va.w = pack2(f1.z, f1.w);
            *(uint4*)&As[(rr * 128 + kc) ^ ((rr & 7) << 3)] = va;
            rr += 16;
        }
    }
    A1s[tid] = A1[tid];
    A1s[tid + 256] = A1[tid + 256];
    __syncthreads();

    // ---- ax FIRST, from LDS (4 threads per row, 32 f each) ----
    {
        const int rr = tid >> 2;
        const int fq = (tid & 3) * 32;
        float s0 = 0.f, s1 = 0.f, s2 = 0.f, s3 = 0.f;
        #pragma unroll
        for (int i = 0; i < 32; i += 8) {
            const bf16x8 v = *(const bf16x8*)&As[(rr * 128 + fq + i) ^ ((rr & 7) << 3)];
            #pragma unroll
            for (int j = 0; j < 8; j++) {
                const float xv = bf2f((unsigned short)v[j]);
                const float* ap = A1s + (fq + i + j) * 4;
                s0 += xv * ap[0]; s1 += xv * ap[1];
                s2 += xv * ap[2]; s3 += xv * ap[3];
            }
        }
        s0 += __shfl_xor(s0, 1); s1 += __shfl_xor(s1, 1);
        s2 += __shfl_xor(s2, 1); s3 += __shfl_xor(s3, 1);
        s0 += __shfl_xor(s0, 2); s1 += __shfl_xor(s1, 2);
        s2 += __shfl_xor(s2, 2); s3 += __shfl_xor(s3, 2);
        const int r = r0 + rr;
        if ((tid & 3) == 0 && r < M)
            *(float4*)(ax + (size_t)r * 4) = make_float4(s0, s1, s2, s3);
    }

    const int lane = tid & 63;
    const int wid = tid >> 6;
    const int wr = wid >> 1, wc = wid & 1;
    const int fr = lane & 15;
    const int kg = (lane >> 4) * 8;

    // hoist A fragments (compile-time indices only; consumed only inside the loop)
    bf16x8 a[2][4];
    #pragma unroll
    for (int m = 0; m < 2; m++) {
        const int ar = wr * 32 + m * 16 + fr;
        #pragma unroll
        for (int ks = 0; ks < 4; ks++)
            a[m][ks] = *(const bf16x8*)&As[(ar * 128 + ks * 32 + kg) ^ ((ar & 7) << 3)];
    }

    for (int ct = 0; ct < 10; ct++) {
        __syncthreads();   // prior Bs reads complete
        {
            int rr = tid >> 4;
            const int kc = (tid & 15) * 8;
            #pragma unroll
            for (int it = 0; it < 4; it++) {
                const uint4 vb = *(const uint4*)(Wc + (size_t)(ct * 64 + rr) * 128 + kc);
                *(uint4*)&Bs[(rr * 128 + kc) ^ ((rr & 7) << 3)] = vb;
                rr += 16;
            }
        }
        __syncthreads();

        f32x4 acc[2][2] = {};
        #pragma unroll
        for (int ks = 0; ks < 4; ks++) {
            bf16x8 b[2];
            #pragma unroll
            for (int n = 0; n < 2; n++) {
                const int br = wc * 32 + n * 16 + fr;
                b[n] = *(const bf16x8*)&Bs[(br * 128 + ks * 32 + kg) ^ ((br & 7) << 3)];
            }
            #pragma unroll
            for (int m = 0; m < 2; m++)
                #pragma unroll
                for (int n = 0; n < 2; n++)
                    acc[m][n] = __builtin_amdgcn_mfma_f32_16x16x32_bf16(a[m][ks], b[n], acc[m][n], 0, 0, 0);
        }

        #pragma unroll
        for (int m = 0; m < 2; m++) {
            #pragma unroll
            for (int n = 0; n < 2; n++) {
                const int ccol = wc * 32 + n * 16 + fr;
                #pragma unroll
                for (int j = 0; j < 4; j++) {
                    const int r = r0 + wr * 32 + m * 16 + (lane >> 4) * 4 + j;
                    if (r < M) {
                        const float v = acc[m][n][j];
                        if (ct < 2) {
                            const int c = ct * 64 + ccol;
                            Xt[(size_t)r * 128 + c] = f2bf(v + bn[c]);
                        } else {
                            const int c = (ct - 2) * 64 + ccol;
                            Xlin[(size_t)r * 512 + c] = f2bf(v);
                        }
                    }
                }
            }
        }
    }
}

// ---------------- MFMA GEMM (E path), A staged once, CT column tiles ----------------
template <bool BF16OUT, int CT, bool AF32>
__global__ __launch_bounds__(256) void gemm2_k(
    const void* __restrict__ Av, const unsigned short* __restrict__ Wt,
    const float* __restrict__ bias, const float* __restrict__ resid,
    void* __restrict__ Cv, int M)
{
    const int NC = CT * 64;
    __shared__ unsigned short As[64 * 128];
    __shared__ unsigned short Bs[64 * 128];
    const int tid = threadIdx.x;
    const int r0 = blockIdx.x * 64;

    {
        int rr = tid >> 4;
        const int kc = (tid & 15) * 8;
        #pragma unroll
        for (int it = 0; it < 4; it++) {
            int r = r0 + rr; if (r > M - 1) r = M - 1;
            uint4 va;
            if (AF32) {
                const float* ap = (const float*)Av + (size_t)r * 128 + kc;
                const float4 f0 = *(const float4*)ap;
                const float4 f1 = *(const float4*)(ap + 4);
                va.x = pack2(f0.x, f0.y); va.y = pack2(f0.z, f0.w);
                va.z = pack2(f1.x, f1.y); va.w = pack2(f1.z, f1.w);
            } else {
                va = *(const uint4*)((const unsigned short*)Av + (size_t)r * 128 + kc);
            }
            *(uint4*)&As[(rr * 128 + kc) ^ ((rr & 7) << 3)] = va;
            rr += 16;
        }
    }
    __syncthreads();

    const int lane = tid & 63;
    const int wid = tid >> 6;
    const int wr = wid >> 1, wc = wid & 1;
    const int fr = lane & 15;
    const int kg = (lane >> 4) * 8;

    bf16x8 a[2][4];
    #pragma unroll
    for (int m = 0; m < 2; m++) {
        const int ar = wr * 32 + m * 16 + fr;
        #pragma unroll
        for (int ks = 0; ks < 4; ks++)
            a[m][ks] = *(const bf16x8*)&As[(ar * 128 + ks * 32 + kg) ^ ((ar & 7) << 3)];
    }

    for (int ct = 0; ct < CT; ct++) {
        const int c0 = ct * 64;
        __syncthreads();
        {
            int rr = tid >> 4;
            const int kc = (tid & 15) * 8;
            #pragma unroll
            for (int it = 0; it < 4; it++) {
                const uint4 vb = *(const uint4*)(Wt + (size_t)(c0 + rr) * 128 + kc);
                *(uint4*)&Bs[(rr * 128 + kc) ^ ((rr & 7) << 3)] = vb;
                rr += 16;
            }
        }
        __syncthreads();

        f32x4 acc[2][2] = {};
        #pragma unroll
        for (int ks = 0; ks < 4; ks++) {
            bf16x8 b[2];
            #pragma unroll
            for (int n = 0; n < 2; n++) {
                const int br = wc * 32 + n * 16 + fr;
                b[n] = *(const bf16x8*)&Bs[(br * 128 + ks * 32 + kg) ^ ((br & 7) << 3)];
            }
            #pragma unroll
            for (int m = 0; m < 2; m++)
                #pragma unroll
                for (int n = 0; n < 2; n++)
                    acc[m][n] = __builtin_amdgcn_mfma_f32_16x16x32_bf16(a[m][ks], b[n], acc[m][n], 0, 0, 0);
        }

        #pragma unroll
        for (int m = 0; m < 2; m++) {
            #pragma unroll
            for (int n = 0; n < 2; n++) {
                const int c = c0 + wc * 32 + n * 16 + (lane & 15);
                #pragma unroll
                for (int j = 0; j < 4; j++) {
                    const int r = r0 + wr * 32 + m * 16 + (lane >> 4) * 4 + j;
                    if (r < M) {
                        float v = acc[m][n][j];
                        if (bias) v += bias[c];
                        if (resid) v += resid[(size_t)r * NC + c];
                        if (BF16OUT) ((unsigned short*)Cv)[(size_t)r * NC + c] = f2bf(v);
                        else         ((float*)Cv)[(size_t)r * NC + c] = v;
                    }
                }
            }
        }
    }
}

// ---- edge aggregation + fused ae: Eres final, ae[e,h] = Eres[e,:]·A2[:,h] ----
__global__ __launch_bounds__(256) void edge_agg_k(
    const int* __restrict__ row, const float* __restrict__ adjv,
    const unsigned short* __restrict__ Xt, const float* __restrict__ A2,
    float* __restrict__ Eres, float* __restrict__ ae)
{
    __shared__ float part[4][4];
    const int s = threadIdx.x >> 7;
    const int e = blockIdx.x * 2 + s;
    const int f = threadIdx.x & 127;
    float v = 0.f;
    if (e < ENUM) {
        float acc = 0.f, deg = 0.f;
        #pragma unroll
        for (int j = 0; j < 8; j++) {
            const int k = e + j * ENUM;
            const float w = adjv[k];
            deg += w;
            acc += w * blo(Xt[(size_t)row[k] * 128 + f]);
        }
        v = Eres[(size_t)e * 128 + f] + acc / deg;
        Eres[(size_t)e * 128 + f] = v;
    }
    const float4 a2 = *(const float4*)(A2 + f * 4);
    float p0 = v * a2.x, p1 = v * a2.y, p2 = v * a2.z, p3 = v * a2.w;
    #pragma unroll
    for (int off = 1; off < 64; off <<= 1) {
        p0 += __shfl_xor(p0, off); p1 += __shfl_xor(p1, off);
        p2 += __shfl_xor(p2, off); p3 += __shfl_xor(p3, off);
    }
    const int w = threadIdx.x >> 6;
    if ((threadIdx.x & 63) == 0) {
        part[w][0] = p0; part[w][1] = p1; part[w][2] = p2; part[w][3] = p3;
    }
    __syncthreads();
    if ((threadIdx.x & 127) == 0 && e < ENUM) {
        float4 o;
        o.x = part[2 * s][0] + part[2 * s + 1][0];
        o.y = part[2 * s][1] + part[2 * s + 1][1];
        o.z = part[2 * s][2] + part[2 * s + 1][2];
        o.w = part[2 * s][3] + part[2 * s + 1][3];
        *(float4*)(ae + (size_t)e * 4) = o;
    }
}

// -------- CSR build --------
__global__ __launch_bounds__(256) void zero_k(unsigned* __restrict__ p, int n)
{
    const int t = blockIdx.x * 256 + threadIdx.x;
    if (t < n) p[t] = 0u;
}

__global__ __launch_bounds__(256) void hist_k(
    const int* __restrict__ row, int* __restrict__ cnt)
{
    const int k = blockIdx.x * 256 + threadIdx.x;
    if (k < NNZ_C) atomicAdd(cnt + row[k], 1);
}

__global__ __launch_bounds__(256) void scan1_k(
    const int* __restrict__ cnt, int* __restrict__ rp, int* __restrict__ bsum, int n)
{
    __shared__ int sh[256];
    const int t = threadIdx.x, g = blockIdx.x * 256 + t;
    const int v = (g < n) ? cnt[g] : 0;
    sh[t] = v; __syncthreads();
    #pragma unroll
    for (int off = 1; off < 256; off <<= 1) {
        const int add = (t >= off) ? sh[t - off] : 0;
        __syncthreads();
        sh[t] += add;
        __syncthreads();
    }
    if (g < n) rp[g] = sh[t] - v;
    if (t == 255) bsum[blockIdx.x] = sh[255];
}

__global__ __launch_bounds__(512) void scan2_k(int* __restrict__ bsum, int nb)
{
    __shared__ int sh[512];
    const int t = threadIdx.x;
    const int v = (t < nb) ? bsum[t] : 0;
    sh[t] = v; __syncthreads();
    #pragma unroll
    for (int off = 1; off < 512; off <<= 1) {
        const int add = (t >= off) ? sh[t - off] : 0;
        __syncthreads();
        sh[t] += add;
        __syncthreads();
    }
    if (t < nb) bsum[t] = sh[t] - v;
}

__global__ __launch_bounds__(256) void scan3_k(
    int* __restrict__ rp, const int* __restrict__ bsum, int* __restrict__ cur, int n)
{
    const int g = blockIdx.x * 256 + threadIdx.x;
    if (g < n) {
        const int v = rp[g] + bsum[g >> 8];
        rp[g] = v;
        cur[g] = v;
    }
    if (g == 0) rp[n] = NNZ_C;
}

__global__ __launch_bounds__(256) void fill_k(
    const int* __restrict__ row, int* __restrict__ cur, int* __restrict__ eidx)
{
    const int k = blockIdx.x * 256 + threadIdx.x;
    if (k < NNZ_C) {
        const int p = atomicAdd(cur + row[k], 1);
        eidx[p] = k;
    }
}

// -------- CSR segment softmax (alpha in k-order) --------
__global__ __launch_bounds__(256) void softmax_csr_k(
    const int* __restrict__ rowptr, const int* __restrict__ eidx,
    const float* __restrict__ ax, const float* __restrict__ ae,
    float* __restrict__ alpha)
{
    const int t = blockIdx.x * 256 + threadIdx.x;
    if (t >= NN * 4) return;
    const int r = t >> 2, h = t & 3;
    const int p0 = rowptr[r], p1 = rowptr[r + 1];
    if (p0 == p1) return;
    const float axv = ax[t];
    float m = -1e30f;
    for (int p = p0; p < p1; ++p) {
        const int c = eidx[p] % ENUM;           // col[k] == k % EN by construction
        float a = axv + ae[c * 4 + h];
        a = (a >= 0.f) ? a : 0.2f * a;
        m = fmaxf(m, a);
    }
    float s = 0.f;
    for (int p = p0; p < p1; ++p) {
        const int k = eidx[p];
        const int c = k % ENUM;
        float a = axv + ae[c * 4 + h];
        a = (a >= 0.f) ? a : 0.2f * a;
        const float e = __expf(a - m);
        s += e;
        alpha[(size_t)k * 4 + h] = e;
    }
    const float rs = 1.f / s;
    for (int p = p0; p < p1; ++p)
        alpha[(size_t)eidx[p] * 4 + h] *= rs;
}

// -------- out_e[e][f][h] = (1/8) sum_j alpha[k,h] * Xlin[row[k]][f][h]  (bf16) ----
__global__ __launch_bounds__(256) void out_e_k(
    const int* __restrict__ row, const float* __restrict__ alpha,
    const unsigned short* __restrict__ Xlin, unsigned short* __restrict__ out_e)
{
    const int e = blockIdx.x * 4 + (threadIdx.x >> 6);
    const int lane = threadIdx.x & 63;
    if (e >= ENUM) return;
    const int f0 = lane * 2;
    float a0 = 0.f, a1 = 0.f, a2 = 0.f, a3 = 0.f;
    float a4 = 0.f, a5 = 0.f, a6 = 0.f, a7 = 0.f;
    #pragma unroll
    for (int j = 0; j < 8; j++) {
        const int k = e + j * ENUM;
        const int r = row[k];
        const float4 al = *(const float4*)(alpha + (size_t)k * 4);
        const uint4 u = *(const uint4*)(Xlin + (size_t)r * 512 + f0 * 4);
        a0 += al.x * blo(u.x); a1 += al.y * bhi(u.x);
        a2 += al.z * blo(u.y); a3 += al.w * bhi(u.y);
        a4 += al.x * blo(u.z); a5 += al.y * bhi(u.z);
        a6 += al.z * blo(u.w); a7 += al.w * bhi(u.w);
    }
    uint4 o;
    o.x = pack2(0.125f * a0, 0.125f * a1);
    o.y = pack2(0.125f * a2, 0.125f * a3);
    o.z = pack2(0.125f * a4, 0.125f * a5);
    o.w = pack2(0.125f * a6, 0.125f * a7);
    *(uint4*)(out_e + (size_t)e * 512 + f0 * 4) = o;
}

// -------- final CSR gather --------
__global__ __launch_bounds__(256) void xgather_k(
    const int* __restrict__ rowptr, const int* __restrict__ eidx,
    const float* __restrict__ adjv, const float* __restrict__ alpha,
    const unsigned short* __restrict__ out_e, const float* __restrict__ bias,
    float* __restrict__ Xres)
{
    const int r = blockIdx.x * 4 + (threadIdx.x >> 6);
    const int lane = threadIdx.x & 63;
    if (r >= NN) return;
    const int p0 = rowptr[r], p1 = rowptr[r + 1];
    const int f0 = lane * 2;
    float a0 = 0.f, a1 = 0.f, ds = 0.f;

#define XG_BODY(P) {                                                          \
        const int k = eidx[P];                                                \
        const int c = k % ENUM;                                               \
        ds += adjv[c];                                                        \
        const float4 al = *(const float4*)(alpha + ((size_t)k << 2));         \
        const uint4 u = *(const uint4*)(out_e + (size_t)c * 512 + f0 * 4);    \
        a0 += al.x * blo(u.x) + al.y * bhi(u.x) + al.z * blo(u.y) + al.w * bhi(u.y); \
        a1 += al.x * blo(u.z) + al.y * bhi(u.z) + al.z * blo(u.w) + al.w * bhi(u.w); \
    }

    int p = p0;
    for (; p + 2 <= p1; p += 2) { XG_BODY(p); XG_BODY(p + 1); }
    if (p < p1) XG_BODY(p);
#undef XG_BODY

    const float w = (p1 > p0) ? 0.25f / ds : 0.f;
    float2 o;
    o.x = bias[f0] + w * a0;
    o.y = bias[f0 + 1] + w * a1;
    *(float2*)(Xres + (size_t)r * 128 + f0) = o;
}

extern "C" void kernel_launch(void* const* d_in, const int* in_sizes, int n_in,
                              void* d_out, int out_size, void* d_ws, size_t ws_size,
                              hipStream_t stream)
{
    const float* X         = (const float*)d_in[0];
    const float* E         = (const float*)d_in[1];
    const int*   adj       = (const int*)d_in[2];
    const float* adjv      = (const float*)d_in[3];
    const float* Wn        = (const float*)d_in[4];
    const float* bn        = (const float*)d_in[5];
    const float* We        = (const float*)d_in[6];
    const float* be        = (const float*)d_in[7];
    const float* Wlin      = (const float*)d_in[8];
    const float* att       = (const float*)d_in[9];
    const float* bias_conv = (const float*)d_in[10];
    const int* row = adj;

    float* Xres = (float*)d_out;
    float* Eres = Xres + (size_t)NN * 128;

    // workspace layout (~161 MB)
    char* wsb = (char*)d_ws;
    unsigned short* out_e = (unsigned short*)(wsb);              // 25.6 MB
    unsigned short* Xt    = (unsigned short*)(wsb + 25600000);   // 25.6 MB
    unsigned short* Xlin  = (unsigned short*)(wsb + 51200000);   // 102.4 MB
    unsigned short* Wcomb = (unsigned short*)(wsb + 153600000);  // 160 KB ([640][128])
    unsigned short* WeT   = (unsigned short*)(wsb + 153763840);  // 32 KB
    float* A1    = (float*)(wsb + 153796608);                    // 2 KB
    float* A2    = (float*)(wsb + 153798656);                    // 2 KB
    float* ax    = (float*)(wsb + 153800704);                    // 1.6 MB
    float* ae    = (float*)(wsb + 155400704);                    // 0.4 MB
    float* alpha = (float*)(wsb + 155800704);                    // 3.2 MB
    int* rowptr  = (int*)(wsb + 159000704);                      // 400,016 B
    int* cnt     = (int*)(wsb + 159400720);                      // 400,000 B
    int* eidx    = (int*)(wsb + 159800720);                      // 800,000 B
    int* bsum    = (int*)(wsb + 160600720);                      // 2 KB

    // ---- CSR build ----
    zero_k<<<(NN + 255) / 256, 256, 0, stream>>>((unsigned*)cnt, NN);
    hist_k<<<(NNZ_C + 255) / 256, 256, 0, stream>>>(row, cnt);
    scan1_k<<<(NN + 255) / 256, 256, 0, stream>>>(cnt, rowptr, bsum, NN);
    scan2_k<<<1, 512, 0, stream>>>(bsum, (NN + 255) / 256);
    scan3_k<<<(NN + 255) / 256, 256, 0, stream>>>(rowptr, bsum, cnt, NN);
    fill_k<<<(NNZ_C + 255) / 256, 256, 0, stream>>>(row, cnt, eidx);

    // ---- weight prep ----
    wtr_k<false><<<64, 256, 0, stream>>>(Wn, Wcomb, 128);                  // rows 0-127
    wtr_k<true><<<256, 256, 0, stream>>>(Wlin, Wcomb + 128 * 128, 512);    // rows 128-639
    wtr_k<false><<<64, 256, 0, stream>>>(We, WeT, 128);
    attw_k<<<1, 256, 0, stream>>>(Wlin, att, A1, A2);

    // ---- fused X pipeline: Xt + Xlin + ax in one pass over X ----
    gemmx_k<<<1563, 256, 0, stream>>>(X, Wcomb, bn, A1, Xt, Xlin, ax, NN);

    // ---- E path ----
    gemm2_k<false, 2, true><<<391, 256, 0, stream>>>(E, WeT, be, E, Eres, ENUM);
    edge_agg_k<<<ENUM / 2, 256, 0, stream>>>(row, adjv, Xt, A2, Eres, ae);

    // ---- CSR softmax ----
    softmax_csr_k<<<(NN * 4) / 256 + 1, 256, 0, stream>>>(rowptr, eidx, ax, ae, alpha);

    // ---- node -> hyperedge ----
    out_e_k<<<ENUM / 4, 256, 0, stream>>>(row, alpha, Xlin, out_e);

    // ---- hyperedge -> node ----
    xgather_k<<<NN / 4, 256, 0, stream>>>(rowptr, eidx, adjv, alpha, out_e, bias_conv, Xres);
}

// Round 12
// 232.868 us; speedup vs baseline: 1.3809x; 1.0411x over previous
//
#include <hip/hip_runtime.h>

#define NN 100000
#define ENUM 25000
#define NNZ_C 200000
// D = 128, H = 4, F = 128, Wlin: [128,512]
// Xlin layout: [row][f][h] via row-permuted Wcomb rows. ax/ae folded into producers.
// Weights stored PRE-SWIZZLED in global (pos ^ ((row&7)<<3)) so B-staging is a
// linear global_load_lds DMA; LDS reads apply the same XOR (guide rule #21).

typedef __attribute__((ext_vector_type(8))) short bf16x8;
typedef __attribute__((ext_vector_type(4))) float f32x4;

__device__ __forceinline__ float bf2f(unsigned short v) {
    return __uint_as_float(((unsigned)v) << 16);
}
__device__ __forceinline__ float blo(unsigned u) { return __uint_as_float(u << 16); }
__device__ __forceinline__ float bhi(unsigned u) { return __uint_as_float(u & 0xFFFF0000u); }
__device__ __forceinline__ unsigned short f2bf(float x) {
    unsigned u = __float_as_uint(x);
    unsigned r = (u + 0x7fff + ((u >> 16) & 1)) >> 16;   // RNE
    return (unsigned short)r;
}
__device__ __forceinline__ unsigned pack2(float a, float b) {
    return (unsigned)f2bf(a) | ((unsigned)f2bf(b) << 16);
}
__device__ __forceinline__ void gload_lds16(const unsigned short* g, unsigned short* l) {
    __builtin_amdgcn_global_load_lds(
        (const __attribute__((address_space(1))) void*)g,
        (__attribute__((address_space(3))) void*)l, 16, 0, 0);
}

// -------- W[128][NC] f32 -> Wt bf16, row cc, stored at swizzled position --------
template <bool PERM>
__global__ __launch_bounds__(256) void wtr_k(
    const float* __restrict__ W, unsigned short* __restrict__ Wt, int NC)
{
    const int t = blockIdx.x * 256 + threadIdx.x;
    if (t >= 128 * NC) return;
    const int c = t % NC, k = t / NC;
    const int cc = PERM ? ((c & 127) * 4 + (c >> 7)) : c;
    const size_t pos = ((size_t)cc * 128 + k) ^ ((cc & 7) << 3);
    Wt[pos] = f2bf(W[t]);
}

// -------- A1/A2[k][h] = sum_f Wlin[k][h*128+f] * att[h*256 + (pair?128:0) + f] ----
__global__ __launch_bounds__(256) void attw_k(
    const float* __restrict__ Wlin, const float* __restrict__ att,
    float* __restrict__ A1, float* __restrict__ A2)
{
    const int t = threadIdx.x;
    const int k = t & 127;
    const int pair = t >> 7;
    const float* wrow = Wlin + (size_t)k * 512;
    float s[4];
    #pragma unroll
    for (int h = 0; h < 4; h++) {
        float acc = 0.f;
        const float* ap = att + h * 256 + pair * 128;
        const float* wp = wrow + h * 128;
        for (int f = 0; f < 128; f++) acc += wp[f] * ap[f];
        s[h] = acc;
    }
    float* dst = (pair ? A2 : A1) + k * 4;
    dst[0] = s[0]; dst[1] = s[1]; dst[2] = s[2]; dst[3] = s[3];
}

// ---- fused X GEMM: Xt = bf16(X@Wn+bn), Xlin = bf16(X@Wlin permuted), ax = X@A1 ----
__global__ __launch_bounds__(256) void gemmx_k(
    const float* __restrict__ X, const unsigned short* __restrict__ Wc,
    const float* __restrict__ bn, const float* __restrict__ A1,
    unsigned short* __restrict__ Xt, unsigned short* __restrict__ Xlin,
    float* __restrict__ ax, int M)
{
    __shared__ unsigned short As[64 * 128];
    __shared__ unsigned short Bs[64 * 128];
    __shared__ float A1s[512];
    const int tid = threadIdx.x;
    const int r0 = blockIdx.x * 64;

    // stage A (f32 -> bf16, swizzled)
    {
        int rr = tid >> 4;
        const int kc = (tid & 15) * 8;
        #pragma unroll
        for (int it = 0; it < 4; it++) {
            int r = r0 + rr; if (r > M - 1) r = M - 1;
            const float* ap = X + (size_t)r * 128 + kc;
            const float4 f0 = *(const float4*)ap;
            const float4 f1 = *(const float4*)(ap + 4);
            uint4 va;
            va.x = pack2(f0.x, f0.y); va.y = pack2(f0.z, f0.w);
            va.z = pack2(f1.x, f1.y); va.w = pack2(f1.z, f1.w);
            *(uint4*)&As[(rr * 128 + kc) ^ ((rr & 7) << 3)] = va;
            rr += 16;
        }
    }
    A1s[tid] = A1[tid];
    A1s[tid + 256] = A1[tid + 256];
    __syncthreads();

    // ---- ax FIRST, from LDS (4 threads per row, 32 f each) ----
    {
        const int rr = tid >> 2;
        const int fq = (tid & 3) * 32;
        float s0 = 0.f, s1 = 0.f, s2 = 0.f, s3 = 0.f;
        #pragma unroll
        for (int i = 0; i < 32; i += 8) {
            const bf16x8 v = *(const bf16x8*)&As[(rr * 128 + fq + i) ^ ((rr & 7) << 3)];
            #pragma unroll
            for (int j = 0; j < 8; j++) {
                const float xv = bf2f((unsigned short)v[j]);
                const float* ap = A1s + (fq + i + j) * 4;
                s0 += xv * ap[0]; s1 += xv * ap[1];
                s2 += xv * ap[2]; s3 += xv * ap[3];
            }
        }
        s0 += __shfl_xor(s0, 1); s1 += __shfl_xor(s1, 1);
        s2 += __shfl_xor(s2, 1); s3 += __shfl_xor(s3, 1);
        s0 += __shfl_xor(s0, 2); s1 += __shfl_xor(s1, 2);
        s2 += __shfl_xor(s2, 2); s3 += __shfl_xor(s3, 2);
        const int r = r0 + rr;
        if ((tid & 3) == 0 && r < M)
            *(float4*)(ax + (size_t)r * 4) = make_float4(s0, s1, s2, s3);
    }

    const int lane = tid & 63;
    const int wid = tid >> 6;
    const int wr = wid >> 1, wc = wid & 1;
    const int fr = lane & 15;
    const int kg = (lane >> 4) * 8;

    // hoist A fragments (compile-time indices only; consumed only inside the loop)
    bf16x8 a[2][4];
    #pragma unroll
    for (int m = 0; m < 2; m++) {
        const int ar = wr * 32 + m * 16 + fr;
        #pragma unroll
        for (int ks = 0; ks < 4; ks++)
            a[m][ks] = *(const bf16x8*)&As[(ar * 128 + ks * 32 + kg) ^ ((ar & 7) << 3)];
    }

    for (int ct = 0; ct < 10; ct++) {
        __syncthreads();   // prior Bs reads complete
        // linear DMA of pre-swizzled 16KB tile: dest = uniform base + lane*16
        {
            const unsigned short* src = Wc + (size_t)ct * 8192 + tid * 8;
            unsigned short* dst = &Bs[tid * 8];
            #pragma unroll
            for (int it = 0; it < 4; it++)
                gload_lds16(src + it * 2048, dst + it * 2048);
        }
        __syncthreads();

        f32x4 acc[2][2] = {};
        #pragma unroll
        for (int ks = 0; ks < 4; ks++) {
            bf16x8 b[2];
            #pragma unroll
            for (int n = 0; n < 2; n++) {
                const int br = wc * 32 + n * 16 + fr;
                b[n] = *(const bf16x8*)&Bs[(br * 128 + ks * 32 + kg) ^ ((br & 7) << 3)];
            }
            #pragma unroll
            for (int m = 0; m < 2; m++)
                #pragma unroll
                for (int n = 0; n < 2; n++)
                    acc[m][n] = __builtin_amdgcn_mfma_f32_16x16x32_bf16(a[m][ks], b[n], acc[m][n], 0, 0, 0);
        }

        #pragma unroll
        for (int m = 0; m < 2; m++) {
            #pragma unroll
            for (int n = 0; n < 2; n++) {
                const int ccol = wc * 32 + n * 16 + fr;
                #pragma unroll
                for (int j = 0; j < 4; j++) {
                    const int r = r0 + wr * 32 + m * 16 + (lane >> 4) * 4 + j;
                    if (r < M) {
                        const float v = acc[m][n][j];
                        if (ct < 2) {
                            const int c = ct * 64 + ccol;
                            Xt[(size_t)r * 128 + c] = f2bf(v + bn[c]);
                        } else {
                            const int c = (ct - 2) * 64 + ccol;
                            Xlin[(size_t)r * 512 + c] = f2bf(v);
                        }
                    }
                }
            }
        }
    }
}

// ---------------- MFMA GEMM (E path), A staged once, CT column tiles ----------------
template <bool BF16OUT, int CT, bool AF32>
__global__ __launch_bounds__(256) void gemm2_k(
    const void* __restrict__ Av, const unsigned short* __restrict__ Wt,
    const float* __restrict__ bias, const float* __restrict__ resid,
    void* __restrict__ Cv, int M)
{
    const int NC = CT * 64;
    __shared__ unsigned short As[64 * 128];
    __shared__ unsigned short Bs[64 * 128];
    const int tid = threadIdx.x;
    const int r0 = blockIdx.x * 64;

    {
        int rr = tid >> 4;
        const int kc = (tid & 15) * 8;
        #pragma unroll
        for (int it = 0; it < 4; it++) {
            int r = r0 + rr; if (r > M - 1) r = M - 1;
            uint4 va;
            if (AF32) {
                const float* ap = (const float*)Av + (size_t)r * 128 + kc;
                const float4 f0 = *(const float4*)ap;
                const float4 f1 = *(const float4*)(ap + 4);
                va.x = pack2(f0.x, f0.y); va.y = pack2(f0.z, f0.w);
                va.z = pack2(f1.x, f1.y); va.w = pack2(f1.z, f1.w);
            } else {
                va = *(const uint4*)((const unsigned short*)Av + (size_t)r * 128 + kc);
            }
            *(uint4*)&As[(rr * 128 + kc) ^ ((rr & 7) << 3)] = va;
            rr += 16;
        }
    }
    __syncthreads();

    const int lane = tid & 63;
    const int wid = tid >> 6;
    const int wr = wid >> 1, wc = wid & 1;
    const int fr = lane & 15;
    const int kg = (lane >> 4) * 8;

    bf16x8 a[2][4];
    #pragma unroll
    for (int m = 0; m < 2; m++) {
        const int ar = wr * 32 + m * 16 + fr;
        #pragma unroll
        for (int ks = 0; ks < 4; ks++)
            a[m][ks] = *(const bf16x8*)&As[(ar * 128 + ks * 32 + kg) ^ ((ar & 7) << 3)];
    }

    for (int ct = 0; ct < CT; ct++) {
        __syncthreads();
        {
            const unsigned short* src = Wt + (size_t)ct * 8192 + tid * 8;
            unsigned short* dst = &Bs[tid * 8];
            #pragma unroll
            for (int it = 0; it < 4; it++)
                gload_lds16(src + it * 2048, dst + it * 2048);
        }
        __syncthreads();

        f32x4 acc[2][2] = {};
        #pragma unroll
        for (int ks = 0; ks < 4; ks++) {
            bf16x8 b[2];
            #pragma unroll
            for (int n = 0; n < 2; n++) {
                const int br = wc * 32 + n * 16 + fr;
                b[n] = *(const bf16x8*)&Bs[(br * 128 + ks * 32 + kg) ^ ((br & 7) << 3)];
            }
            #pragma unroll
            for (int m = 0; m < 2; m++)
                #pragma unroll
                for (int n = 0; n < 2; n++)
                    acc[m][n] = __builtin_amdgcn_mfma_f32_16x16x32_bf16(a[m][ks], b[n], acc[m][n], 0, 0, 0);
        }

        const int c0 = ct * 64;
        #pragma unroll
        for (int m = 0; m < 2; m++) {
            #pragma unroll
            for (int n = 0; n < 2; n++) {
                const int c = c0 + wc * 32 + n * 16 + (lane & 15);
                #pragma unroll
                for (int j = 0; j < 4; j++) {
                    const int r = r0 + wr * 32 + m * 16 + (lane >> 4) * 4 + j;
                    if (r < M) {
                        float v = acc[m][n][j];
                        if (bias) v += bias[c];
                        if (resid) v += resid[(size_t)r * NC + c];
                        if (BF16OUT) ((unsigned short*)Cv)[(size_t)r * NC + c] = f2bf(v);
                        else         ((float*)Cv)[(size_t)r * NC + c] = v;
                    }
                }
            }
        }
    }
}

// ---- edge aggregation + fused ae: Eres final, ae[e,h] = Eres[e,:]·A2[:,h] ----
__global__ __launch_bounds__(256) void edge_agg_k(
    const int* __restrict__ row, const float* __restrict__ adjv,
    const unsigned short* __restrict__ Xt, const float* __restrict__ A2,
    float* __restrict__ Eres, float* __restrict__ ae)
{
    __shared__ float part[4][4];
    const int s = threadIdx.x >> 7;
    const int e = blockIdx.x * 2 + s;
    const int f = threadIdx.x & 127;
    float v = 0.f;
    if (e < ENUM) {
        float acc = 0.f, deg = 0.f;
        #pragma unroll
        for (int j = 0; j < 8; j++) {
            const int k = e + j * ENUM;
            const float w = adjv[k];
            deg += w;
            acc += w * blo(Xt[(size_t)row[k] * 128 + f]);
        }
        v = Eres[(size_t)e * 128 + f] + acc / deg;
        Eres[(size_t)e * 128 + f] = v;
    }
    const float4 a2 = *(const float4*)(A2 + f * 4);
    float p0 = v * a2.x, p1 = v * a2.y, p2 = v * a2.z, p3 = v * a2.w;
    #pragma unroll
    for (int off = 1; off < 64; off <<= 1) {
        p0 += __shfl_xor(p0, off); p1 += __shfl_xor(p1, off);
        p2 += __shfl_xor(p2, off); p3 += __shfl_xor(p3, off);
    }
    const int w = threadIdx.x >> 6;
    if ((threadIdx.x & 63) == 0) {
        part[w][0] = p0; part[w][1] = p1; part[w][2] = p2; part[w][3] = p3;
    }
    __syncthreads();
    if ((threadIdx.x & 127) == 0 && e < ENUM) {
        float4 o;
        o.x = part[2 * s][0] + part[2 * s + 1][0];
        o.y = part[2 * s][1] + part[2 * s + 1][1];
        o.z = part[2 * s][2] + part[2 * s + 1][2];
        o.w = part[2 * s][3] + part[2 * s + 1][3];
        *(float4*)(ae + (size_t)e * 4) = o;
    }
}

// -------- CSR build --------
__global__ __launch_bounds__(256) void zero_k(unsigned* __restrict__ p, int n)
{
    const int t = blockIdx.x * 256 + threadIdx.x;
    if (t < n) p[t] = 0u;
}

__global__ __launch_bounds__(256) void hist_k(
    const int* __restrict__ row, int* __restrict__ cnt)
{
    const int k = blockIdx.x * 256 + threadIdx.x;
    if (k < NNZ_C) atomicAdd(cnt + row[k], 1);
}

__global__ __launch_bounds__(256) void scan1_k(
    const int* __restrict__ cnt, int* __restrict__ rp, int* __restrict__ bsum, int n)
{
    __shared__ int sh[256];
    const int t = threadIdx.x, g = blockIdx.x * 256 + t;
    const int v = (g < n) ? cnt[g] : 0;
    sh[t] = v; __syncthreads();
    #pragma unroll
    for (int off = 1; off < 256; off <<= 1) {
        const int add = (t >= off) ? sh[t - off] : 0;
        __syncthreads();
        sh[t] += add;
        __syncthreads();
    }
    if (g < n) rp[g] = sh[t] - v;
    if (t == 255) bsum[blockIdx.x] = sh[255];
}

__global__ __launch_bounds__(512) void scan2_k(int* __restrict__ bsum, int nb)
{
    __shared__ int sh[512];
    const int t = threadIdx.x;
    const int v = (t < nb) ? bsum[t] : 0;
    sh[t] = v; __syncthreads();
    #pragma unroll
    for (int off = 1; off < 512; off <<= 1) {
        const int add = (t >= off) ? sh[t - off] : 0;
        __syncthreads();
        sh[t] += add;
        __syncthreads();
    }
    if (t < nb) bsum[t] = sh[t] - v;
}

__global__ __launch_bounds__(256) void scan3_k(
    int* __restrict__ rp, const int* __restrict__ bsum, int* __restrict__ cur, int n)
{
    const int g = blockIdx.x * 256 + threadIdx.x;
    if (g < n) {
        const int v = rp[g] + bsum[g >> 8];
        rp[g] = v;
        cur[g] = v;
    }
    if (g == 0) rp[n] = NNZ_C;
}

__global__ __launch_bounds__(256) void fill_k(
    const int* __restrict__ row, int* __restrict__ cur, int* __restrict__ eidx)
{
    const int k = blockIdx.x * 256 + threadIdx.x;
    if (k < NNZ_C) {
        const int p = atomicAdd(cur + row[k], 1);
        eidx[p] = k;
    }
}

// -------- CSR segment softmax (alpha in k-order, single scattered write) --------
__global__ __launch_bounds__(256) void softmax_csr_k(
    const int* __restrict__ rowptr, const int* __restrict__ eidx,
    const float* __restrict__ ax, const float* __restrict__ ae,
    float* __restrict__ alpha)
{
    const int t = blockIdx.x * 256 + threadIdx.x;
    if (t >= NN * 4) return;
    const int r = t >> 2, h = t & 3;
    const int p0 = rowptr[r], p1 = rowptr[r + 1];
    if (p0 == p1) return;
    const float axv = ax[t];
    float m = -1e30f;
    for (int p = p0; p < p1; ++p) {
        const int c = eidx[p] % ENUM;           // col[k] == k % EN by construction
        float a = axv + ae[c * 4 + h];
        a = (a >= 0.f) ? a : 0.2f * a;
        m = fmaxf(m, a);
    }
    float s = 0.f;
    for (int p = p0; p < p1; ++p) {
        const int c = eidx[p] % ENUM;
        float a = axv + ae[c * 4 + h];
        a = (a >= 0.f) ? a : 0.2f * a;
        s += __expf(a - m);
    }
    const float rs = 1.f / s;
    for (int p = p0; p < p1; ++p) {
        const int k = eidx[p];
        const int c = k % ENUM;
        float a = axv + ae[c * 4 + h];
        a = (a >= 0.f) ? a : 0.2f * a;
        alpha[(size_t)k * 4 + h] = __expf(a - m) * rs;
    }
}

// -------- out_e[e][f][h] = (1/8) sum_j alpha[k,h] * Xlin[row[k]][f][h]  (bf16) ----
__global__ __launch_bounds__(256) void out_e_k(
    const int* __restrict__ row, const float* __restrict__ alpha,
    const unsigned short* __restrict__ Xlin, unsigned short* __restrict__ out_e)
{
    const int e = blockIdx.x * 4 + (threadIdx.x >> 6);
    const int lane = threadIdx.x & 63;
    if (e >= ENUM) return;
    const int f0 = lane * 2;
    float a0 = 0.f, a1 = 0.f, a2 = 0.f, a3 = 0.f;
    float a4 = 0.f, a5 = 0.f, a6 = 0.f, a7 = 0.f;
    #pragma unroll
    for (int j = 0; j < 8; j++) {
        const int k = e + j * ENUM;
        const int r = row[k];
        const float4 al = *(const float4*)(alpha + (size_t)k * 4);
        const uint4 u = *(const uint4*)(Xlin + (size_t)r * 512 + f0 * 4);
        a0 += al.x * blo(u.x); a1 += al.y * bhi(u.x);
        a2 += al.z * blo(u.y); a3 += al.w * bhi(u.y);
        a4 += al.x * blo(u.z); a5 += al.y * bhi(u.z);
        a6 += al.z * blo(u.w); a7 += al.w * bhi(u.w);
    }
    uint4 o;
    o.x = pack2(0.125f * a0, 0.125f * a1);
    o.y = pack2(0.125f * a2, 0.125f * a3);
    o.z = pack2(0.125f * a4, 0.125f * a5);
    o.w = pack2(0.125f * a6, 0.125f * a7);
    *(uint4*)(out_e + (size_t)e * 512 + f0 * 4) = o;
}

// -------- final CSR gather --------
__global__ __launch_bounds__(256) void xgather_k(
    const int* __restrict__ rowptr, const int* __restrict__ eidx,
    const float* __restrict__ adjv, const float* __restrict__ alpha,
    const unsigned short* __restrict__ out_e, const float* __restrict__ bias,
    float* __restrict__ Xres)
{
    const int r = blockIdx.x * 4 + (threadIdx.x >> 6);
    const int lane = threadIdx.x & 63;
    if (r >= NN) return;
    const int p0 = rowptr[r], p1 = rowptr[r + 1];
    const int f0 = lane * 2;
    float a0 = 0.f, a1 = 0.f, ds = 0.f;

#define XG_BODY(P) {                                                          \
        const int k = eidx[P];                                                \
        const int c = k % ENUM;                                               \
        ds += adjv[c];                                                        \
        const float4 al = *(const float4*)(alpha + ((size_t)k << 2));         \
        const uint4 u = *(const uint4*)(out_e + (size_t)c * 512 + f0 * 4);    \
        a0 += al.x * blo(u.x) + al.y * bhi(u.x) + al.z * blo(u.y) + al.w * bhi(u.y); \
        a1 += al.x * blo(u.z) + al.y * bhi(u.z) + al.z * blo(u.w) + al.w * bhi(u.w); \
    }

    int p = p0;
    for (; p + 2 <= p1; p += 2) { XG_BODY(p); XG_BODY(p + 1); }
    if (p < p1) XG_BODY(p);
#undef XG_BODY

    const float w = (p1 > p0) ? 0.25f / ds : 0.f;
    float2 o;
    o.x = bias[f0] + w * a0;
    o.y = bias[f0 + 1] + w * a1;
    *(float2*)(Xres + (size_t)r * 128 + f0) = o;
}

extern "C" void kernel_launch(void* const* d_in, const int* in_sizes, int n_in,
                              void* d_out, int out_size, void* d_ws, size_t ws_size,
                              hipStream_t stream)
{
    const float* X         = (const float*)d_in[0];
    const float* E         = (const float*)d_in[1];
    const int*   adj       = (const int*)d_in[2];
    const float* adjv      = (const float*)d_in[3];
    const float* Wn        = (const float*)d_in[4];
    const float* bn        = (const float*)d_in[5];
    const float* We        = (const float*)d_in[6];
    const float* be        = (const float*)d_in[7];
    const float* Wlin      = (const float*)d_in[8];
    const float* att       = (const float*)d_in[9];
    const float* bias_conv = (const float*)d_in[10];
    const int* row = adj;

    float* Xres = (float*)d_out;
    float* Eres = Xres + (size_t)NN * 128;

    // workspace layout (~161 MB)
    char* wsb = (char*)d_ws;
    unsigned short* out_e = (unsigned short*)(wsb);              // 25.6 MB
    unsigned short* Xt    = (unsigned short*)(wsb + 25600000);   // 25.6 MB
    unsigned short* Xlin  = (unsigned short*)(wsb + 51200000);   // 102.4 MB
    unsigned short* Wcomb = (unsigned short*)(wsb + 153600000);  // 160 KB ([640][128], swizzled)
    unsigned short* WeT   = (unsigned short*)(wsb + 153763840);  // 32 KB (swizzled)
    float* A1    = (float*)(wsb + 153796608);                    // 2 KB
    float* A2    = (float*)(wsb + 153798656);                    // 2 KB
    float* ax    = (float*)(wsb + 153800704);                    // 1.6 MB
    float* ae    = (float*)(wsb + 155400704);                    // 0.4 MB
    float* alpha = (float*)(wsb + 155800704);                    // 3.2 MB
    int* rowptr  = (int*)(wsb + 159000704);                      // 400,016 B
    int* cnt     = (int*)(wsb + 159400720);                      // 400,000 B
    int* eidx    = (int*)(wsb + 159800720);                      // 800,000 B
    int* bsum    = (int*)(wsb + 160600720);                      // 2 KB

    // ---- CSR build ----
    zero_k<<<(NN + 255) / 256, 256, 0, stream>>>((unsigned*)cnt, NN);
    hist_k<<<(NNZ_C + 255) / 256, 256, 0, stream>>>(row, cnt);
    scan1_k<<<(NN + 255) / 256, 256, 0, stream>>>(cnt, rowptr, bsum, NN);
    scan2_k<<<1, 512, 0, stream>>>(bsum, (NN + 255) / 256);
    scan3_k<<<(NN + 255) / 256, 256, 0, stream>>>(rowptr, bsum, cnt, NN);
    fill_k<<<(NNZ_C + 255) / 256, 256, 0, stream>>>(row, cnt, eidx);

    // ---- weight prep (pre-swizzled global layout) ----
    wtr_k<false><<<64, 256, 0, stream>>>(Wn, Wcomb, 128);                  // rows 0-127
    wtr_k<true><<<256, 256, 0, stream>>>(Wlin, Wcomb + 128 * 128, 512);    // rows 128-639
    wtr_k<false><<<64, 256, 0, stream>>>(We, WeT, 128);
    attw_k<<<1, 256, 0, stream>>>(Wlin, att, A1, A2);

    // ---- fused X pipeline: Xt + Xlin + ax in one pass over X ----
    gemmx_k<<<1563, 256, 0, stream>>>(X, Wcomb, bn, A1, Xt, Xlin, ax, NN);

    // ---- E path ----
    gemm2_k<false, 2, true><<<391, 256, 0, stream>>>(E, WeT, be, E, Eres, ENUM);
    edge_agg_k<<<ENUM / 2, 256, 0, stream>>>(row, adjv, Xt, A2, Eres, ae);

    // ---- CSR softmax ----
    softmax_csr_k<<<(NN * 4) / 256 + 1, 256, 0, stream>>>(rowptr, eidx, ax, ae, alpha);

    // ---- node -> hyperedge ----
    out_e_k<<<ENUM / 4, 256, 0, stream>>>(row, alpha, Xlin, out_e);

    // ---- hyperedge -> node ----
    xgather_k<<<NN / 4, 256, 0, stream>>>(rowptr, eidx, adjv, alpha, out_e, bias_conv, Xres);
}

// Round 13
// 227.455 us; speedup vs baseline: 1.4137x; 1.0238x over previous
//
#include <hip/hip_runtime.h>

#define NN 100000
#define ENUM 25000
#define NNZ_C 200000
// D = 128, H = 4, F = 128, Wlin: [128,512]
// Xlin layout: [row][f][h] via row-permuted Wlp rows. ax/ae folded into producers.
// E-path: agg = B^-1 A^T X (gather, bf16) ; Eres = agg@Wn + E@We + (bn+be) + E.
// Weights PRE-SWIZZLED in global (pos ^ ((row&7)<<3)) -> linear global_load_lds DMA.

typedef __attribute__((ext_vector_type(8))) short bf16x8;
typedef __attribute__((ext_vector_type(4))) float f32x4;

__device__ __forceinline__ float bf2f(unsigned short v) {
    return __uint_as_float(((unsigned)v) << 16);
}
__device__ __forceinline__ float blo(unsigned u) { return __uint_as_float(u << 16); }
__device__ __forceinline__ float bhi(unsigned u) { return __uint_as_float(u & 0xFFFF0000u); }
__device__ __forceinline__ unsigned short f2bf(float x) {
    unsigned u = __float_as_uint(x);
    unsigned r = (u + 0x7fff + ((u >> 16) & 1)) >> 16;   // RNE
    return (unsigned short)r;
}
__device__ __forceinline__ unsigned pack2(float a, float b) {
    return (unsigned)f2bf(a) | ((unsigned)f2bf(b) << 16);
}
__device__ __forceinline__ void gload_lds16(const unsigned short* g, unsigned short* l) {
    __builtin_amdgcn_global_load_lds(
        (const __attribute__((address_space(1))) void*)g,
        (__attribute__((address_space(3))) void*)l, 16, 0, 0);
}

// -------- W[128][NC] f32 -> Wt bf16, row cc, stored at swizzled position --------
template <bool PERM>
__global__ __launch_bounds__(256) void wtr_k(
    const float* __restrict__ W, unsigned short* __restrict__ Wt, int NC)
{
    const int t = blockIdx.x * 256 + threadIdx.x;
    if (t >= 128 * NC) return;
    const int c = t % NC, k = t / NC;
    const int cc = PERM ? ((c & 127) * 4 + (c >> 7)) : c;
    const size_t pos = ((size_t)cc * 128 + k) ^ ((cc & 7) << 3);
    Wt[pos] = f2bf(W[t]);
}

// -------- A1/A2[k][h] = Wlin-att dots; bnbe = bn + be --------
__global__ __launch_bounds__(256) void attw_k(
    const float* __restrict__ Wlin, const float* __restrict__ att,
    const float* __restrict__ bn, const float* __restrict__ be,
    float* __restrict__ A1, float* __restrict__ A2, float* __restrict__ bnbe)
{
    const int t = threadIdx.x;
    const int k = t & 127;
    const int pair = t >> 7;
    const float* wrow = Wlin + (size_t)k * 512;
    float s[4];
    #pragma unroll
    for (int h = 0; h < 4; h++) {
        float acc = 0.f;
        const float* ap = att + h * 256 + pair * 128;
        const float* wp = wrow + h * 128;
        for (int f = 0; f < 128; f++) acc += wp[f] * ap[f];
        s[h] = acc;
    }
    float* dst = (pair ? A2 : A1) + k * 4;
    dst[0] = s[0]; dst[1] = s[1]; dst[2] = s[2]; dst[3] = s[3];
    if (t < 128) bnbe[t] = bn[t] + be[t];
}

// ---- fused X GEMM: Xlin = bf16(X@Wlin permuted), ax = X@A1 ----
// Wlp: [512][128] bf16 (row-permuted WlinT, pre-swizzled)
__global__ __launch_bounds__(256) void gemmx_k(
    const float* __restrict__ X, const unsigned short* __restrict__ Wlp,
    const float* __restrict__ A1,
    unsigned short* __restrict__ Xlin, float* __restrict__ ax, int M)
{
    __shared__ unsigned short As[64 * 128];
    __shared__ unsigned short Bs[64 * 128];
    __shared__ float A1s[512];
    const int tid = threadIdx.x;
    const int r0 = blockIdx.x * 64;

    // stage A (f32 -> bf16, swizzled)
    {
        int rr = tid >> 4;
        const int kc = (tid & 15) * 8;
        #pragma unroll
        for (int it = 0; it < 4; it++) {
            int r = r0 + rr; if (r > M - 1) r = M - 1;
            const float* ap = X + (size_t)r * 128 + kc;
            const float4 f0 = *(const float4*)ap;
            const float4 f1 = *(const float4*)(ap + 4);
            uint4 va;
            va.x = pack2(f0.x, f0.y); va.y = pack2(f0.z, f0.w);
            va.z = pack2(f1.x, f1.y); va.w = pack2(f1.z, f1.w);
            *(uint4*)&As[(rr * 128 + kc) ^ ((rr & 7) << 3)] = va;
            rr += 16;
        }
    }
    A1s[tid] = A1[tid];
    A1s[tid + 256] = A1[tid + 256];
    __syncthreads();

    // ---- ax FIRST, from LDS (4 threads per row, 32 f each) ----
    {
        const int rr = tid >> 2;
        const int fq = (tid & 3) * 32;
        float s0 = 0.f, s1 = 0.f, s2 = 0.f, s3 = 0.f;
        #pragma unroll
        for (int i = 0; i < 32; i += 8) {
            const bf16x8 v = *(const bf16x8*)&As[(rr * 128 + fq + i) ^ ((rr & 7) << 3)];
            #pragma unroll
            for (int j = 0; j < 8; j++) {
                const float xv = bf2f((unsigned short)v[j]);
                const float* ap = A1s + (fq + i + j) * 4;
                s0 += xv * ap[0]; s1 += xv * ap[1];
                s2 += xv * ap[2]; s3 += xv * ap[3];
            }
        }
        s0 += __shfl_xor(s0, 1); s1 += __shfl_xor(s1, 1);
        s2 += __shfl_xor(s2, 1); s3 += __shfl_xor(s3, 1);
        s0 += __shfl_xor(s0, 2); s1 += __shfl_xor(s1, 2);
        s2 += __shfl_xor(s2, 2); s3 += __shfl_xor(s3, 2);
        const int r = r0 + rr;
        if ((tid & 3) == 0 && r < M)
            *(float4*)(ax + (size_t)r * 4) = make_float4(s0, s1, s2, s3);
    }

    const int lane = tid & 63;
    const int wid = tid >> 6;
    const int wr = wid >> 1, wc = wid & 1;
    const int fr = lane & 15;
    const int kg = (lane >> 4) * 8;

    bf16x8 a[2][4];
    #pragma unroll
    for (int m = 0; m < 2; m++) {
        const int ar = wr * 32 + m * 16 + fr;
        #pragma unroll
        for (int ks = 0; ks < 4; ks++)
            a[m][ks] = *(const bf16x8*)&As[(ar * 128 + ks * 32 + kg) ^ ((ar & 7) << 3)];
    }

    for (int ct = 0; ct < 8; ct++) {
        __syncthreads();
        {
            const unsigned short* src = Wlp + (size_t)ct * 8192 + tid * 8;
            unsigned short* dst = &Bs[tid * 8];
            #pragma unroll
            for (int it = 0; it < 4; it++)
                gload_lds16(src + it * 2048, dst + it * 2048);
        }
        __syncthreads();

        f32x4 acc[2][2] = {};
        #pragma unroll
        for (int ks = 0; ks < 4; ks++) {
            bf16x8 b[2];
            #pragma unroll
            for (int n = 0; n < 2; n++) {
                const int br = wc * 32 + n * 16 + fr;
                b[n] = *(const bf16x8*)&Bs[(br * 128 + ks * 32 + kg) ^ ((br & 7) << 3)];
            }
            #pragma unroll
            for (int m = 0; m < 2; m++)
                #pragma unroll
                for (int n = 0; n < 2; n++)
                    acc[m][n] = __builtin_amdgcn_mfma_f32_16x16x32_bf16(a[m][ks], b[n], acc[m][n], 0, 0, 0);
        }

        #pragma unroll
        for (int m = 0; m < 2; m++) {
            #pragma unroll
            for (int n = 0; n < 2; n++) {
                const int c = ct * 64 + wc * 32 + n * 16 + fr;
                #pragma unroll
                for (int j = 0; j < 4; j++) {
                    const int r = r0 + wr * 32 + m * 16 + (lane >> 4) * 4 + j;
                    if (r < M)
                        Xlin[(size_t)r * 512 + c] = f2bf(acc[m][n][j]);
                }
            }
        }
    }
}

// -------- agg[e] = (1/deg) sum_j w * X[row[k]]  (bf16 out) --------
__global__ __launch_bounds__(256) void agg_k(
    const int* __restrict__ row, const float* __restrict__ adjv,
    const float* __restrict__ X, unsigned short* __restrict__ agg)
{
    const int e = blockIdx.x * 4 + (threadIdx.x >> 6);
    const int lane = threadIdx.x & 63;
    if (e >= ENUM) return;
    const int f0 = lane * 2;
    float a0 = 0.f, a1 = 0.f, deg = 0.f;
    #pragma unroll
    for (int j = 0; j < 8; j++) {
        const int k = e + j * ENUM;
        const float w = adjv[k];
        deg += w;
        const float2 x = *(const float2*)(X + (size_t)row[k] * 128 + f0);
        a0 += w * x.x; a1 += w * x.y;
    }
    const float rs = 1.f / deg;
    ((unsigned*)agg)[(size_t)e * 64 + lane] = pack2(a0 * rs, a1 * rs);
}

// ---- combined E GEMM: Eres = agg@Wn + E@We + bnbe + E  (f32 out) ----
__global__ __launch_bounds__(256) void gemme_k(
    const unsigned short* __restrict__ agg, const float* __restrict__ E,
    const unsigned short* __restrict__ WnT, const unsigned short* __restrict__ WeT,
    const float* __restrict__ bnbe, float* __restrict__ Eres, int M)
{
    __shared__ unsigned short Ag[64 * 128];
    __shared__ unsigned short Ae[64 * 128];
    __shared__ unsigned short Bw[64 * 128];
    __shared__ unsigned short Bv[64 * 128];
    const int tid = threadIdx.x;
    const int r0 = blockIdx.x * 64;

    {
        int rr = tid >> 4;
        const int kc = (tid & 15) * 8;
        #pragma unroll
        for (int it = 0; it < 4; it++) {
            int r = r0 + rr; if (r > M - 1) r = M - 1;
            const uint4 vg = *(const uint4*)(agg + (size_t)r * 128 + kc);
            const float* ep = E + (size_t)r * 128 + kc;
            const float4 f0 = *(const float4*)ep;
            const float4 f1 = *(const float4*)(ep + 4);
            uint4 ve;
            ve.x = pack2(f0.x, f0.y); ve.y = pack2(f0.z, f0.w);
            ve.z = pack2(f1.x, f1.y); ve.w = pack2(f1.z, f1.w);
            const int idx = (rr * 128 + kc) ^ ((rr & 7) << 3);
            *(uint4*)&Ag[idx] = vg;
            *(uint4*)&Ae[idx] = ve;
            rr += 16;
        }
    }
    __syncthreads();

    const int lane = tid & 63;
    const int wid = tid >> 6;
    const int wr = wid >> 1, wc = wid & 1;
    const int fr = lane & 15;
    const int kg = (lane >> 4) * 8;

    bf16x8 ag[2][4], ae_[2][4];
    #pragma unroll
    for (int m = 0; m < 2; m++) {
        const int ar = wr * 32 + m * 16 + fr;
        #pragma unroll
        for (int ks = 0; ks < 4; ks++) {
            const int idx = (ar * 128 + ks * 32 + kg) ^ ((ar & 7) << 3);
            ag[m][ks] = *(const bf16x8*)&Ag[idx];
            ae_[m][ks] = *(const bf16x8*)&Ae[idx];
        }
    }

    for (int ct = 0; ct < 2; ct++) {
        __syncthreads();
        {
            const unsigned short* s1 = WnT + (size_t)ct * 8192 + tid * 8;
            const unsigned short* s2 = WeT + (size_t)ct * 8192 + tid * 8;
            unsigned short* d1 = &Bw[tid * 8];
            unsigned short* d2 = &Bv[tid * 8];
            #pragma unroll
            for (int it = 0; it < 4; it++) {
                gload_lds16(s1 + it * 2048, d1 + it * 2048);
                gload_lds16(s2 + it * 2048, d2 + it * 2048);
            }
        }
        __syncthreads();

        f32x4 acc[2][2] = {};
        #pragma unroll
        for (int ks = 0; ks < 4; ks++) {
            bf16x8 bw[2], bv[2];
            #pragma unroll
            for (int n = 0; n < 2; n++) {
                const int br = wc * 32 + n * 16 + fr;
                const int idx = (br * 128 + ks * 32 + kg) ^ ((br & 7) << 3);
                bw[n] = *(const bf16x8*)&Bw[idx];
                bv[n] = *(const bf16x8*)&Bv[idx];
            }
            #pragma unroll
            for (int m = 0; m < 2; m++)
                #pragma unroll
                for (int n = 0; n < 2; n++) {
                    acc[m][n] = __builtin_amdgcn_mfma_f32_16x16x32_bf16(ag[m][ks], bw[n], acc[m][n], 0, 0, 0);
                    acc[m][n] = __builtin_amdgcn_mfma_f32_16x16x32_bf16(ae_[m][ks], bv[n], acc[m][n], 0, 0, 0);
                }
        }

        #pragma unroll
        for (int m = 0; m < 2; m++) {
            #pragma unroll
            for (int n = 0; n < 2; n++) {
                const int c = ct * 64 + wc * 32 + n * 16 + fr;
                #pragma unroll
                for (int j = 0; j < 4; j++) {
                    const int r = r0 + wr * 32 + m * 16 + (lane >> 4) * 4 + j;
                    if (r < M)
                        Eres[(size_t)r * 128 + c] = acc[m][n][j] + bnbe[c] + E[(size_t)r * 128 + c];
                }
            }
        }
    }
}

// -------- ae[e,h] = Eres[e,:] . A2[:,h] --------
__global__ __launch_bounds__(256) void ae_k(
    const float* __restrict__ Eres, const float* __restrict__ A2,
    float* __restrict__ ae)
{
    const int e = blockIdx.x * 4 + (threadIdx.x >> 6);
    const int lane = threadIdx.x & 63;
    if (e >= ENUM) return;
    const int f0 = lane * 2;
    const float2 v = *(const float2*)(Eres + (size_t)e * 128 + f0);
    const float4 a0 = *(const float4*)(A2 + f0 * 4);
    const float4 a1 = *(const float4*)(A2 + f0 * 4 + 4);
    float s0 = v.x * a0.x + v.y * a1.x;
    float s1 = v.x * a0.y + v.y * a1.y;
    float s2 = v.x * a0.z + v.y * a1.z;
    float s3 = v.x * a0.w + v.y * a1.w;
    #pragma unroll
    for (int off = 1; off < 64; off <<= 1) {
        s0 += __shfl_xor(s0, off); s1 += __shfl_xor(s1, off);
        s2 += __shfl_xor(s2, off); s3 += __shfl_xor(s3, off);
    }
    if (lane == 0) *(float4*)(ae + (size_t)e * 4) = make_float4(s0, s1, s2, s3);
}

// -------- CSR build --------
__global__ __launch_bounds__(256) void zero_k(unsigned* __restrict__ p, int n)
{
    const int t = blockIdx.x * 256 + threadIdx.x;
    if (t < n) p[t] = 0u;
}

__global__ __launch_bounds__(256) void hist_k(
    const int* __restrict__ row, int* __restrict__ cnt)
{
    const int k = blockIdx.x * 256 + threadIdx.x;
    if (k < NNZ_C) atomicAdd(cnt + row[k], 1);
}

__global__ __launch_bounds__(256) void scan1_k(
    const int* __restrict__ cnt, int* __restrict__ rp, int* __restrict__ bsum, int n)
{
    __shared__ int sh[256];
    const int t = threadIdx.x, g = blockIdx.x * 256 + t;
    const int v = (g < n) ? cnt[g] : 0;
    sh[t] = v; __syncthreads();
    #pragma unroll
    for (int off = 1; off < 256; off <<= 1) {
        const int add = (t >= off) ? sh[t - off] : 0;
        __syncthreads();
        sh[t] += add;
        __syncthreads();
    }
    if (g < n) rp[g] = sh[t] - v;
    if (t == 255) bsum[blockIdx.x] = sh[255];
}

__global__ __launch_bounds__(512) void scan2_k(int* __restrict__ bsum, int nb)
{
    __shared__ int sh[512];
    const int t = threadIdx.x;
    const int v = (t < nb) ? bsum[t] : 0;
    sh[t] = v; __syncthreads();
    #pragma unroll
    for (int off = 1; off < 512; off <<= 1) {
        const int add = (t >= off) ? sh[t - off] : 0;
        __syncthreads();
        sh[t] += add;
        __syncthreads();
    }
    if (t < nb) bsum[t] = sh[t] - v;
}

__global__ __launch_bounds__(256) void scan3_k(
    int* __restrict__ rp, const int* __restrict__ bsum, int* __restrict__ cur, int n)
{
    const int g = blockIdx.x * 256 + threadIdx.x;
    if (g < n) {
        const int v = rp[g] + bsum[g >> 8];
        rp[g] = v;
        cur[g] = v;
    }
    if (g == 0) rp[n] = NNZ_C;
}

__global__ __launch_bounds__(256) void fill_k(
    const int* __restrict__ row, int* __restrict__ cur, int* __restrict__ eidx)
{
    const int k = blockIdx.x * 256 + threadIdx.x;
    if (k < NNZ_C) {
        const int p = atomicAdd(cur + row[k], 1);
        eidx[p] = k;
    }
}

// -------- CSR segment softmax (alpha in k-order, single scattered write) --------
__global__ __launch_bounds__(256) void softmax_csr_k(
    const int* __restrict__ rowptr, const int* __restrict__ eidx,
    const float* __restrict__ ax, const float* __restrict__ ae,
    float* __restrict__ alpha)
{
    const int t = blockIdx.x * 256 + threadIdx.x;
    if (t >= NN * 4) return;
    const int r = t >> 2, h = t & 3;
    const int p0 = rowptr[r], p1 = rowptr[r + 1];
    if (p0 == p1) return;
    const float axv = ax[t];
    float m = -1e30f;
    for (int p = p0; p < p1; ++p) {
        const int c = eidx[p] % ENUM;           // col[k] == k % EN by construction
        float a = axv + ae[c * 4 + h];
        a = (a >= 0.f) ? a : 0.2f * a;
        m = fmaxf(m, a);
    }
    float s = 0.f;
    for (int p = p0; p < p1; ++p) {
        const int c = eidx[p] % ENUM;
        float a = axv + ae[c * 4 + h];
        a = (a >= 0.f) ? a : 0.2f * a;
        s += __expf(a - m);
    }
    const float rs = 1.f / s;
    for (int p = p0; p < p1; ++p) {
        const int k = eidx[p];
        const int c = k % ENUM;
        float a = axv + ae[c * 4 + h];
        a = (a >= 0.f) ? a : 0.2f * a;
        alpha[(size_t)k * 4 + h] = __expf(a - m) * rs;
    }
}

// -------- out_e[e][f][h] = (1/8) sum_j alpha[k,h] * Xlin[row[k]][f][h]  (bf16) ----
__global__ __launch_bounds__(256) void out_e_k(
    const int* __restrict__ row, const float* __restrict__ alpha,
    const unsigned short* __restrict__ Xlin, unsigned short* __restrict__ out_e)
{
    const int e = blockIdx.x * 4 + (threadIdx.x >> 6);
    const int lane = threadIdx.x & 63;
    if (e >= ENUM) return;
    const int f0 = lane * 2;
    float a0 = 0.f, a1 = 0.f, a2 = 0.f, a3 = 0.f;
    float a4 = 0.f, a5 = 0.f, a6 = 0.f, a7 = 0.f;
    #pragma unroll
    for (int j = 0; j < 8; j++) {
        const int k = e + j * ENUM;
        const int r = row[k];
        const float4 al = *(const float4*)(alpha + (size_t)k * 4);
        const uint4 u = *(const uint4*)(Xlin + (size_t)r * 512 + f0 * 4);
        a0 += al.x * blo(u.x); a1 += al.y * bhi(u.x);
        a2 += al.z * blo(u.y); a3 += al.w * bhi(u.y);
        a4 += al.x * blo(u.z); a5 += al.y * bhi(u.z);
        a6 += al.z * blo(u.w); a7 += al.w * bhi(u.w);
    }
    uint4 o;
    o.x = pack2(0.125f * a0, 0.125f * a1);
    o.y = pack2(0.125f * a2, 0.125f * a3);
    o.z = pack2(0.125f * a4, 0.125f * a5);
    o.w = pack2(0.125f * a6, 0.125f * a7);
    *(uint4*)(out_e + (size_t)e * 512 + f0 * 4) = o;
}

// -------- final CSR gather --------
__global__ __launch_bounds__(256) void xgather_k(
    const int* __restrict__ rowptr, const int* __restrict__ eidx,
    const float* __restrict__ adjv, const float* __restrict__ alpha,
    const unsigned short* __restrict__ out_e, const float* __restrict__ bias,
    float* __restrict__ Xres)
{
    const int r = blockIdx.x * 4 + (threadIdx.x >> 6);
    const int lane = threadIdx.x & 63;
    if (r >= NN) return;
    const int p0 = rowptr[r], p1 = rowptr[r + 1];
    const int f0 = lane * 2;
    float a0 = 0.f, a1 = 0.f, ds = 0.f;

#define XG_BODY(P) {                                                          \
        const int k = eidx[P];                                                \
        const int c = k % ENUM;                                               \
        ds += adjv[c];                                                        \
        const float4 al = *(const float4*)(alpha + ((size_t)k << 2));         \
        const uint4 u = *(const uint4*)(out_e + (size_t)c * 512 + f0 * 4);    \
        a0 += al.x * blo(u.x) + al.y * bhi(u.x) + al.z * blo(u.y) + al.w * bhi(u.y); \
        a1 += al.x * blo(u.z) + al.y * bhi(u.z) + al.z * blo(u.w) + al.w * bhi(u.w); \
    }

    int p = p0;
    for (; p + 2 <= p1; p += 2) { XG_BODY(p); XG_BODY(p + 1); }
    if (p < p1) XG_BODY(p);
#undef XG_BODY

    const float w = (p1 > p0) ? 0.25f / ds : 0.f;
    float2 o;
    o.x = bias[f0] + w * a0;
    o.y = bias[f0 + 1] + w * a1;
    *(float2*)(Xres + (size_t)r * 128 + f0) = o;
}

extern "C" void kernel_launch(void* const* d_in, const int* in_sizes, int n_in,
                              void* d_out, int out_size, void* d_ws, size_t ws_size,
                              hipStream_t stream)
{
    const float* X         = (const float*)d_in[0];
    const float* E         = (const float*)d_in[1];
    const int*   adj       = (const int*)d_in[2];
    const float* adjv      = (const float*)d_in[3];
    const float* Wn        = (const float*)d_in[4];
    const float* bn        = (const float*)d_in[5];
    const float* We        = (const float*)d_in[6];
    const float* be        = (const float*)d_in[7];
    const float* Wlin      = (const float*)d_in[8];
    const float* att       = (const float*)d_in[9];
    const float* bias_conv = (const float*)d_in[10];
    const int* row = adj;

    float* Xres = (float*)d_out;
    float* Eres = Xres + (size_t)NN * 128;

    // workspace layout (~161 MB)
    char* wsb = (char*)d_ws;
    unsigned short* out_e = (unsigned short*)(wsb);              // 25.6 MB
    unsigned short* agg   = (unsigned short*)(wsb + 25600000);   // 6.5 MB
    unsigned short* Xlin  = (unsigned short*)(wsb + 51200000);   // 102.4 MB
    unsigned short* Wlp   = (unsigned short*)(wsb + 153600000);  // 128 KB (perm+swz)
    unsigned short* WnT   = (unsigned short*)(wsb + 153731072);  // 32 KB (swz)
    unsigned short* WeT   = (unsigned short*)(wsb + 153763840);  // 32 KB (swz)
    float* A1    = (float*)(wsb + 153796608);                    // 2 KB
    float* A2    = (float*)(wsb + 153798656);                    // 2 KB
    float* bnbe  = (float*)(wsb + 153800704);                    // 512 B (rsv 2 KB)
    float* ax    = (float*)(wsb + 153802752);                    // 1.6 MB
    float* ae    = (float*)(wsb + 155402752);                    // 0.4 MB
    float* alpha = (float*)(wsb + 155802752);                    // 3.2 MB
    int* rowptr  = (int*)(wsb + 159002752);                      // 400,016 B
    int* cnt     = (int*)(wsb + 159402768);                      // 400,000 B
    int* eidx    = (int*)(wsb + 159802768);                      // 800,000 B
    int* bsum    = (int*)(wsb + 160602768);                      // 2 KB

    // ---- CSR build ----
    zero_k<<<(NN + 255) / 256, 256, 0, stream>>>((unsigned*)cnt, NN);
    hist_k<<<(NNZ_C + 255) / 256, 256, 0, stream>>>(row, cnt);
    scan1_k<<<(NN + 255) / 256, 256, 0, stream>>>(cnt, rowptr, bsum, NN);
    scan2_k<<<1, 512, 0, stream>>>(bsum, (NN + 255) / 256);
    scan3_k<<<(NN + 255) / 256, 256, 0, stream>>>(rowptr, bsum, cnt, NN);
    fill_k<<<(NNZ_C + 255) / 256, 256, 0, stream>>>(row, cnt, eidx);

    // ---- weight prep ----
    wtr_k<true><<<256, 256, 0, stream>>>(Wlin, Wlp, 512);
    wtr_k<false><<<64, 256, 0, stream>>>(Wn, WnT, 128);
    wtr_k<false><<<64, 256, 0, stream>>>(We, WeT, 128);
    attw_k<<<1, 256, 0, stream>>>(Wlin, att, bn, be, A1, A2, bnbe);

    // ---- X pipeline: Xlin + ax in one pass over X ----
    gemmx_k<<<1563, 256, 0, stream>>>(X, Wlp, A1, Xlin, ax, NN);

    // ---- E path: agg -> combined GEMM -> ae ----
    agg_k<<<ENUM / 4, 256, 0, stream>>>(row, adjv, X, agg);
    gemme_k<<<391, 256, 0, stream>>>(agg, E, WnT, WeT, bnbe, Eres, ENUM);
    ae_k<<<ENUM / 4, 256, 0, stream>>>(Eres, A2, ae);

    // ---- CSR softmax ----
    softmax_csr_k<<<(NN * 4) / 256 + 1, 256, 0, stream>>>(rowptr, eidx, ax, ae, alpha);

    // ---- node -> hyperedge ----
    out_e_k<<<ENUM / 4, 256, 0, stream>>>(row, alpha, Xlin, out_e);

    // ---- hyperedge -> node ----
    xgather_k<<<NN / 4, 256, 0, stream>>>(rowptr, eidx, adjv, alpha, out_e, bias_conv, Xres);
}

// Round 15
// 226.147 us; speedup vs baseline: 1.4219x; 1.0058x over previous
//
#include <hip/hip_runtime.h>

#define NN 100000
#define ENUM 25000
#define NNZ_C 200000
// D = 128, H = 4, F = 128, Wlin: [128,512]
// Xlin layout: [row][f][h] via row-permuted Wlp rows. ax/ae folded into producers.
// E-path: agg = B^-1 A^T X (gather, bf16) ; Eres = agg@Wn + E@We + (bn+be) + E.
// Weights PRE-SWIZZLED in global (pos ^ ((row&7)<<3)) -> linear global_load_lds DMA.

typedef __attribute__((ext_vector_type(8))) short bf16x8;
typedef __attribute__((ext_vector_type(4))) float f32x4;

__device__ __forceinline__ float bf2f(unsigned short v) {
    return __uint_as_float(((unsigned)v) << 16);
}
__device__ __forceinline__ float blo(unsigned u) { return __uint_as_float(u << 16); }
__device__ __forceinline__ float bhi(unsigned u) { return __uint_as_float(u & 0xFFFF0000u); }
__device__ __forceinline__ unsigned short f2bf(float x) {
    unsigned u = __float_as_uint(x);
    unsigned r = (u + 0x7fff + ((u >> 16) & 1)) >> 16;   // RNE
    return (unsigned short)r;
}
__device__ __forceinline__ unsigned pack2(float a, float b) {
    return (unsigned)f2bf(a) | ((unsigned)f2bf(b) << 16);
}
__device__ __forceinline__ void gload_lds16(const unsigned short* g, unsigned short* l) {
    __builtin_amdgcn_global_load_lds(
        (const __attribute__((address_space(1))) void*)g,
        (__attribute__((address_space(3))) void*)l, 16, 0, 0);
}

// -------- W[128][NC] f32 -> Wt bf16, row cc, stored at swizzled position --------
template <bool PERM>
__global__ __launch_bounds__(256) void wtr_k(
    const float* __restrict__ W, unsigned short* __restrict__ Wt, int NC)
{
    const int t = blockIdx.x * 256 + threadIdx.x;
    if (t >= 128 * NC) return;
    const int c = t % NC, k = t / NC;
    const int cc = PERM ? ((c & 127) * 4 + (c >> 7)) : c;
    const size_t pos = ((size_t)cc * 128 + k) ^ ((cc & 7) << 3);
    Wt[pos] = f2bf(W[t]);
}

// -------- A1/A2[k][h] = Wlin-att dots; bnbe = bn + be --------
__global__ __launch_bounds__(256) void attw_k(
    const float* __restrict__ Wlin, const float* __restrict__ att,
    const float* __restrict__ bn, const float* __restrict__ be,
    float* __restrict__ A1, float* __restrict__ A2, float* __restrict__ bnbe)
{
    const int t = threadIdx.x;
    const int k = t & 127;
    const int pair = t >> 7;
    const float* wrow = Wlin + (size_t)k * 512;
    float s[4];
    #pragma unroll
    for (int h = 0; h < 4; h++) {
        float acc = 0.f;
        const float* ap = att + h * 256 + pair * 128;
        const float* wp = wrow + h * 128;
        for (int f = 0; f < 128; f++) acc += wp[f] * ap[f];
        s[h] = acc;
    }
    float* dst = (pair ? A2 : A1) + k * 4;
    dst[0] = s[0]; dst[1] = s[1]; dst[2] = s[2]; dst[3] = s[3];
    if (t < 128) bnbe[t] = bn[t] + be[t];
}

// ---- fused X GEMM (BM=64, R13-proven): Xlin = bf16(X@Wlin permuted), ax = X@A1 ----
__global__ __launch_bounds__(256) void gemmx_k(
    const float* __restrict__ X, const unsigned short* __restrict__ Wlp,
    const float* __restrict__ A1,
    unsigned short* __restrict__ Xlin, float* __restrict__ ax, int M)
{
    __shared__ unsigned short As[64 * 128];
    __shared__ unsigned short Bs[64 * 128];
    __shared__ float A1s[512];
    const int tid = threadIdx.x;
    const int r0 = blockIdx.x * 64;

    // stage A (f32 -> bf16, swizzled)
    {
        int rr = tid >> 4;
        const int kc = (tid & 15) * 8;
        #pragma unroll
        for (int it = 0; it < 4; it++) {
            int r = r0 + rr; if (r > M - 1) r = M - 1;
            const float* ap = X + (size_t)r * 128 + kc;
            const float4 f0 = *(const float4*)ap;
            const float4 f1 = *(const float4*)(ap + 4);
            uint4 va;
            va.x = pack2(f0.x, f0.y); va.y = pack2(f0.z, f0.w);
            va.z = pack2(f1.x, f1.y); va.w = pack2(f1.z, f1.w);
            *(uint4*)&As[(rr * 128 + kc) ^ ((rr & 7) << 3)] = va;
            rr += 16;
        }
    }
    A1s[tid] = A1[tid];
    A1s[tid + 256] = A1[tid + 256];
    __syncthreads();

    // ---- ax FIRST, from LDS (4 threads per row, 32 f each) ----
    {
        const int rr = tid >> 2;
        const int fq = (tid & 3) * 32;
        float s0 = 0.f, s1 = 0.f, s2 = 0.f, s3 = 0.f;
        #pragma unroll
        for (int i = 0; i < 32; i += 8) {
            const bf16x8 v = *(const bf16x8*)&As[(rr * 128 + fq + i) ^ ((rr & 7) << 3)];
            #pragma unroll
            for (int j = 0; j < 8; j++) {
                const float xv = bf2f((unsigned short)v[j]);
                const float* ap = A1s + (fq + i + j) * 4;
                s0 += xv * ap[0]; s1 += xv * ap[1];
                s2 += xv * ap[2]; s3 += xv * ap[3];
            }
        }
        s0 += __shfl_xor(s0, 1); s1 += __shfl_xor(s1, 1);
        s2 += __shfl_xor(s2, 1); s3 += __shfl_xor(s3, 1);
        s0 += __shfl_xor(s0, 2); s1 += __shfl_xor(s1, 2);
        s2 += __shfl_xor(s2, 2); s3 += __shfl_xor(s3, 2);
        const int r = r0 + rr;
        if ((tid & 3) == 0 && r < M)
            *(float4*)(ax + (size_t)r * 4) = make_float4(s0, s1, s2, s3);
    }

    const int lane = tid & 63;
    const int wid = tid >> 6;
    const int wr = wid >> 1, wc = wid & 1;
    const int fr = lane & 15;
    const int kg = (lane >> 4) * 8;

    bf16x8 a[2][4];
    #pragma unroll
    for (int m = 0; m < 2; m++) {
        const int ar = wr * 32 + m * 16 + fr;
        #pragma unroll
        for (int ks = 0; ks < 4; ks++)
            a[m][ks] = *(const bf16x8*)&As[(ar * 128 + ks * 32 + kg) ^ ((ar & 7) << 3)];
    }

    for (int ct = 0; ct < 8; ct++) {
        __syncthreads();
        {
            const unsigned short* src = Wlp + (size_t)ct * 8192 + tid * 8;
            unsigned short* dst = &Bs[tid * 8];
            #pragma unroll
            for (int it = 0; it < 4; it++)
                gload_lds16(src + it * 2048, dst + it * 2048);
        }
        __syncthreads();

        f32x4 acc[2][2] = {};
        #pragma unroll
        for (int ks = 0; ks < 4; ks++) {
            bf16x8 b[2];
            #pragma unroll
            for (int n = 0; n < 2; n++) {
                const int br = wc * 32 + n * 16 + fr;
                b[n] = *(const bf16x8*)&Bs[(br * 128 + ks * 32 + kg) ^ ((br & 7) << 3)];
            }
            #pragma unroll
            for (int m = 0; m < 2; m++)
                #pragma unroll
                for (int n = 0; n < 2; n++)
                    acc[m][n] = __builtin_amdgcn_mfma_f32_16x16x32_bf16(a[m][ks], b[n], acc[m][n], 0, 0, 0);
        }

        #pragma unroll
        for (int m = 0; m < 2; m++) {
            #pragma unroll
            for (int n = 0; n < 2; n++) {
                const int c = ct * 64 + wc * 32 + n * 16 + fr;
                #pragma unroll
                for (int j = 0; j < 4; j++) {
                    const int r = r0 + wr * 32 + m * 16 + (lane >> 4) * 4 + j;
                    if (r < M)
                        Xlin[(size_t)r * 512 + c] = f2bf(acc[m][n][j]);
                }
            }
        }
    }
}

// -------- agg[e] = (1/deg) sum_j w * X[row[k]]  (bf16 out) --------
__global__ __launch_bounds__(256) void agg_k(
    const int* __restrict__ row, const float* __restrict__ adjv,
    const float* __restrict__ X, unsigned short* __restrict__ agg)
{
    const int e = blockIdx.x * 4 + (threadIdx.x >> 6);
    const int lane = threadIdx.x & 63;
    if (e >= ENUM) return;
    const int f0 = lane * 2;
    float a0 = 0.f, a1 = 0.f, deg = 0.f;
    #pragma unroll
    for (int j = 0; j < 8; j++) {
        const int k = e + j * ENUM;
        const float w = adjv[k];
        deg += w;
        const float2 x = *(const float2*)(X + (size_t)row[k] * 128 + f0);
        a0 += w * x.x; a1 += w * x.y;
    }
    const float rs = 1.f / deg;
    ((unsigned*)agg)[(size_t)e * 64 + lane] = pack2(a0 * rs, a1 * rs);
}

// ---- combined E GEMM: Eres = agg@Wn + E@We + bnbe + E  (f32 out) ----
__global__ __launch_bounds__(256) void gemme_k(
    const unsigned short* __restrict__ agg, const float* __restrict__ E,
    const unsigned short* __restrict__ WnT, const unsigned short* __restrict__ WeT,
    const float* __restrict__ bnbe, float* __restrict__ Eres, int M)
{
    __shared__ unsigned short Ag[64 * 128];
    __shared__ unsigned short Ae[64 * 128];
    __shared__ unsigned short Bw[64 * 128];
    __shared__ unsigned short Bv[64 * 128];
    const int tid = threadIdx.x;
    const int r0 = blockIdx.x * 64;

    {
        int rr = tid >> 4;
        const int kc = (tid & 15) * 8;
        #pragma unroll
        for (int it = 0; it < 4; it++) {
            int r = r0 + rr; if (r > M - 1) r = M - 1;
            const uint4 vg = *(const uint4*)(agg + (size_t)r * 128 + kc);
            const float* ep = E + (size_t)r * 128 + kc;
            const float4 f0 = *(const float4*)ep;
            const float4 f1 = *(const float4*)(ep + 4);
            uint4 ve;
            ve.x = pack2(f0.x, f0.y); ve.y = pack2(f0.z, f0.w);
            ve.z = pack2(f1.x, f1.y); ve.w = pack2(f1.z, f1.w);
            const int idx = (rr * 128 + kc) ^ ((rr & 7) << 3);
            *(uint4*)&Ag[idx] = vg;
            *(uint4*)&Ae[idx] = ve;
            rr += 16;
        }
    }
    __syncthreads();

    const int lane = tid & 63;
    const int wid = tid >> 6;
    const int wr = wid >> 1, wc = wid & 1;
    const int fr = lane & 15;
    const int kg = (lane >> 4) * 8;

    bf16x8 ag[2][4], ae_[2][4];
    #pragma unroll
    for (int m = 0; m < 2; m++) {
        const int ar = wr * 32 + m * 16 + fr;
        #pragma unroll
        for (int ks = 0; ks < 4; ks++) {
            const int idx = (ar * 128 + ks * 32 + kg) ^ ((ar & 7) << 3);
            ag[m][ks] = *(const bf16x8*)&Ag[idx];
            ae_[m][ks] = *(const bf16x8*)&Ae[idx];
        }
    }

    for (int ct = 0; ct < 2; ct++) {
        __syncthreads();
        {
            const unsigned short* s1 = WnT + (size_t)ct * 8192 + tid * 8;
            const unsigned short* s2 = WeT + (size_t)ct * 8192 + tid * 8;
            unsigned short* d1 = &Bw[tid * 8];
            unsigned short* d2 = &Bv[tid * 8];
            #pragma unroll
            for (int it = 0; it < 4; it++) {
                gload_lds16(s1 + it * 2048, d1 + it * 2048);
                gload_lds16(s2 + it * 2048, d2 + it * 2048);
            }
        }
        __syncthreads();

        f32x4 acc[2][2] = {};
        #pragma unroll
        for (int ks = 0; ks < 4; ks++) {
            bf16x8 bw[2], bv[2];
            #pragma unroll
            for (int n = 0; n < 2; n++) {
                const int br = wc * 32 + n * 16 + fr;
                const int idx = (br * 128 + ks * 32 + kg) ^ ((br & 7) << 3);
                bw[n] = *(const bf16x8*)&Bw[idx];
                bv[n] = *(const bf16x8*)&Bv[idx];
            }
            #pragma unroll
            for (int m = 0; m < 2; m++)
                #pragma unroll
                for (int n = 0; n < 2; n++) {
                    acc[m][n] = __builtin_amdgcn_mfma_f32_16x16x32_bf16(ag[m][ks], bw[n], acc[m][n], 0, 0, 0);
                    acc[m][n] = __builtin_amdgcn_mfma_f32_16x16x32_bf16(ae_[m][ks], bv[n], acc[m][n], 0, 0, 0);
                }
        }

        #pragma unroll
        for (int m = 0; m < 2; m++) {
            #pragma unroll
            for (int n = 0; n < 2; n++) {
                const int c = ct * 64 + wc * 32 + n * 16 + fr;
                #pragma unroll
                for (int j = 0; j < 4; j++) {
                    const int r = r0 + wr * 32 + m * 16 + (lane >> 4) * 4 + j;
                    if (r < M)
                        Eres[(size_t)r * 128 + c] = acc[m][n][j] + bnbe[c] + E[(size_t)r * 128 + c];
                }
            }
        }
    }
}

// -------- ae[e,h] = Eres[e,:] . A2[:,h] --------
__global__ __launch_bounds__(256) void ae_k(
    const float* __restrict__ Eres, const float* __restrict__ A2,
    float* __restrict__ ae)
{
    const int e = blockIdx.x * 4 + (threadIdx.x >> 6);
    const int lane = threadIdx.x & 63;
    if (e >= ENUM) return;
    const int f0 = lane * 2;
    const float2 v = *(const float2*)(Eres + (size_t)e * 128 + f0);
    const float4 a0 = *(const float4*)(A2 + f0 * 4);
    const float4 a1 = *(const float4*)(A2 + f0 * 4 + 4);
    float s0 = v.x * a0.x + v.y * a1.x;
    float s1 = v.x * a0.y + v.y * a1.y;
    float s2 = v.x * a0.z + v.y * a1.z;
    float s3 = v.x * a0.w + v.y * a1.w;
    #pragma unroll
    for (int off = 1; off < 64; off <<= 1) {
        s0 += __shfl_xor(s0, off); s1 += __shfl_xor(s1, off);
        s2 += __shfl_xor(s2, off); s3 += __shfl_xor(s3, off);
    }
    if (lane == 0) *(float4*)(ae + (size_t)e * 4) = make_float4(s0, s1, s2, s3);
}

// -------- CSR build --------
__global__ __launch_bounds__(256) void zero_k(unsigned* __restrict__ p, int n)
{
    const int t = blockIdx.x * 256 + threadIdx.x;
    if (t < n) p[t] = 0u;
}

__global__ __launch_bounds__(256) void hist_k(
    const int* __restrict__ row, int* __restrict__ cnt)
{
    const int k = blockIdx.x * 256 + threadIdx.x;
    if (k < NNZ_C) atomicAdd(cnt + row[k], 1);
}

__global__ __launch_bounds__(256) void scan1_k(
    const int* __restrict__ cnt, int* __restrict__ rp, int* __restrict__ bsum, int n)
{
    __shared__ int sh[256];
    const int t = threadIdx.x, g = blockIdx.x * 256 + t;
    const int v = (g < n) ? cnt[g] : 0;
    sh[t] = v; __syncthreads();
    #pragma unroll
    for (int off = 1; off < 256; off <<= 1) {
        const int add = (t >= off) ? sh[t - off] : 0;
        __syncthreads();
        sh[t] += add;
        __syncthreads();
    }
    if (g < n) rp[g] = sh[t] - v;
    if (t == 255) bsum[blockIdx.x] = sh[255];
}

__global__ __launch_bounds__(512) void scan2_k(int* __restrict__ bsum, int nb)
{
    __shared__ int sh[512];
    const int t = threadIdx.x;
    const int v = (t < nb) ? bsum[t] : 0;
    sh[t] = v; __syncthreads();
    #pragma unroll
    for (int off = 1; off < 512; off <<= 1) {
        const int add = (t >= off) ? sh[t - off] : 0;
        __syncthreads();
        sh[t] += add;
        __syncthreads();
    }
    if (t < nb) bsum[t] = sh[t] - v;
}

__global__ __launch_bounds__(256) void scan3_k(
    int* __restrict__ rp, const int* __restrict__ bsum, int* __restrict__ cur, int n)
{
    const int g = blockIdx.x * 256 + threadIdx.x;
    if (g < n) {
        const int v = rp[g] + bsum[g >> 8];
        rp[g] = v;
        cur[g] = v;
    }
    if (g == 0) rp[n] = NNZ_C;
}

__global__ __launch_bounds__(256) void fill_k(
    const int* __restrict__ row, int* __restrict__ cur, int* __restrict__ eidx)
{
    const int k = blockIdx.x * 256 + threadIdx.x;
    if (k < NNZ_C) {
        const int p = atomicAdd(cur + row[k], 1);
        eidx[p] = k;
    }
}

// -------- CSR softmax: one thread per row, 4 heads via float4 --------
// writes alpha[k] (k-order, for out_e) and alphag[p] (CSR order, for xgather)
__global__ __launch_bounds__(256) void softmax_csr_k(
    const int* __restrict__ rowptr, const int* __restrict__ eidx,
    const float* __restrict__ ax, const float* __restrict__ ae,
    float* __restrict__ alpha, float* __restrict__ alphag)
{
    const int r = blockIdx.x * 256 + threadIdx.x;
    if (r >= NN) return;
    const int p0 = rowptr[r], p1 = rowptr[r + 1];
    if (p0 == p1) return;
    const float4 axv = *(const float4*)(ax + (size_t)r * 4);

#define LRELU4(a) { a.x = (a.x >= 0.f) ? a.x : 0.2f * a.x;                    \
                    a.y = (a.y >= 0.f) ? a.y : 0.2f * a.y;                    \
                    a.z = (a.z >= 0.f) ? a.z : 0.2f * a.z;                    \
                    a.w = (a.w >= 0.f) ? a.w : 0.2f * a.w; }

    float4 m = make_float4(-1e30f, -1e30f, -1e30f, -1e30f);
    for (int p = p0; p < p1; ++p) {
        const int c = eidx[p] % ENUM;
        float4 a = *(const float4*)(ae + (size_t)c * 4);
        a.x += axv.x; a.y += axv.y; a.z += axv.z; a.w += axv.w;
        LRELU4(a);
        m.x = fmaxf(m.x, a.x); m.y = fmaxf(m.y, a.y);
        m.z = fmaxf(m.z, a.z); m.w = fmaxf(m.w, a.w);
    }
    float4 s = make_float4(0.f, 0.f, 0.f, 0.f);
    for (int p = p0; p < p1; ++p) {
        const int c = eidx[p] % ENUM;
        float4 a = *(const float4*)(ae + (size_t)c * 4);
        a.x += axv.x; a.y += axv.y; a.z += axv.z; a.w += axv.w;
        LRELU4(a);
        s.x += __expf(a.x - m.x); s.y += __expf(a.y - m.y);
        s.z += __expf(a.z - m.z); s.w += __expf(a.w - m.w);
    }
    const float4 rs = make_float4(1.f / s.x, 1.f / s.y, 1.f / s.z, 1.f / s.w);
    for (int p = p0; p < p1; ++p) {
        const int k = eidx[p];
        const int c = k % ENUM;
        float4 a = *(const float4*)(ae + (size_t)c * 4);
        a.x += axv.x; a.y += axv.y; a.z += axv.z; a.w += axv.w;
        LRELU4(a);
        float4 v;
        v.x = __expf(a.x - m.x) * rs.x; v.y = __expf(a.y - m.y) * rs.y;
        v.z = __expf(a.z - m.z) * rs.z; v.w = __expf(a.w - m.w) * rs.w;
        *(float4*)(alpha + ((size_t)k << 2)) = v;
        *(float4*)(alphag + ((size_t)p << 2)) = v;
    }
#undef LRELU4
}

// -------- out_e[e][f][h] = (1/8) sum_j alpha[k,h] * Xlin[row[k]][f][h]  (bf16) ----
__global__ __launch_bounds__(256) void out_e_k(
    const int* __restrict__ row, const float* __restrict__ alpha,
    const unsigned short* __restrict__ Xlin, unsigned short* __restrict__ out_e)
{
    const int e = blockIdx.x * 4 + (threadIdx.x >> 6);
    const int lane = threadIdx.x & 63;
    if (e >= ENUM) return;
    const int f0 = lane * 2;
    float a0 = 0.f, a1 = 0.f, a2 = 0.f, a3 = 0.f;
    float a4 = 0.f, a5 = 0.f, a6 = 0.f, a7 = 0.f;
    #pragma unroll
    for (int j = 0; j < 8; j++) {
        const int k = e + j * ENUM;
        const int r = row[k];
        const float4 al = *(const float4*)(alpha + (size_t)k * 4);
        const uint4 u = *(const uint4*)(Xlin + (size_t)r * 512 + f0 * 4);
        a0 += al.x * blo(u.x); a1 += al.y * bhi(u.x);
        a2 += al.z * blo(u.y); a3 += al.w * bhi(u.y);
        a4 += al.x * blo(u.z); a5 += al.y * bhi(u.z);
        a6 += al.z * blo(u.w); a7 += al.w * bhi(u.w);
    }
    uint4 o;
    o.x = pack2(0.125f * a0, 0.125f * a1);
    o.y = pack2(0.125f * a2, 0.125f * a3);
    o.z = pack2(0.125f * a4, 0.125f * a5);
    o.w = pack2(0.125f * a6, 0.125f * a7);
    *(uint4*)(out_e + (size_t)e * 512 + f0 * 4) = o;
}

// -------- final CSR gather (alphag sequential) --------
__global__ __launch_bounds__(256) void xgather_k(
    const int* __restrict__ rowptr, const int* __restrict__ eidx,
    const float* __restrict__ adjv, const float* __restrict__ alphag,
    const unsigned short* __restrict__ out_e, const float* __restrict__ bias,
    float* __restrict__ Xres)
{
    const int r = blockIdx.x * 4 + (threadIdx.x >> 6);
    const int lane = threadIdx.x & 63;
    if (r >= NN) return;
    const int p0 = rowptr[r], p1 = rowptr[r + 1];
    const int f0 = lane * 2;
    float a0 = 0.f, a1 = 0.f, ds = 0.f;

#define XG_BODY(P) {                                                          \
        const int c = eidx[P] % ENUM;                                         \
        ds += adjv[c];                                                        \
        const float4 al = *(const float4*)(alphag + ((size_t)(P) << 2));      \
        const uint4 u = *(const uint4*)(out_e + (size_t)c * 512 + f0 * 4);    \
        a0 += al.x * blo(u.x) + al.y * bhi(u.x) + al.z * blo(u.y) + al.w * bhi(u.y); \
        a1 += al.x * blo(u.z) + al.y * bhi(u.z) + al.z * blo(u.w) + al.w * bhi(u.w); \
    }

    int p = p0;
    for (; p + 2 <= p1; p += 2) { XG_BODY(p); XG_BODY(p + 1); }
    if (p < p1) XG_BODY(p);
#undef XG_BODY

    const float w = (p1 > p0) ? 0.25f / ds : 0.f;
    float2 o;
    o.x = bias[f0] + w * a0;
    o.y = bias[f0 + 1] + w * a1;
    *(float2*)(Xres + (size_t)r * 128 + f0) = o;
}

extern "C" void kernel_launch(void* const* d_in, const int* in_sizes, int n_in,
                              void* d_out, int out_size, void* d_ws, size_t ws_size,
                              hipStream_t stream)
{
    const float* X         = (const float*)d_in[0];
    const float* E         = (const float*)d_in[1];
    const int*   adj       = (const int*)d_in[2];
    const float* adjv      = (const float*)d_in[3];
    const float* Wn        = (const float*)d_in[4];
    const float* bn        = (const float*)d_in[5];
    const float* We        = (const float*)d_in[6];
    const float* be        = (const float*)d_in[7];
    const float* Wlin      = (const float*)d_in[8];
    const float* att       = (const float*)d_in[9];
    const float* bias_conv = (const float*)d_in[10];
    const int* row = adj;

    float* Xres = (float*)d_out;
    float* Eres = Xres + (size_t)NN * 128;

    // workspace layout (~164 MB)
    char* wsb = (char*)d_ws;
    unsigned short* out_e = (unsigned short*)(wsb);              // 25.6 MB
    unsigned short* agg   = (unsigned short*)(wsb + 25600000);   // 6.5 MB
    unsigned short* Xlin  = (unsigned short*)(wsb + 51200000);   // 102.4 MB
    unsigned short* Wlp   = (unsigned short*)(wsb + 153600000);  // 128 KB (perm+swz)
    unsigned short* WnT   = (unsigned short*)(wsb + 153731072);  // 32 KB (swz)
    unsigned short* WeT   = (unsigned short*)(wsb + 153763840);  // 32 KB (swz)
    float* A1    = (float*)(wsb + 153796608);                    // 2 KB
    float* A2    = (float*)(wsb + 153798656);                    // 2 KB
    float* bnbe  = (float*)(wsb + 153800704);                    // 512 B (rsv 2 KB)
    float* ax    = (float*)(wsb + 153802752);                    // 1.6 MB
    float* ae    = (float*)(wsb + 155402752);                    // 0.4 MB
    float* alpha = (float*)(wsb + 155802752);                    // 3.2 MB
    int* rowptr  = (int*)(wsb + 159002752);                      // 400,016 B
    int* cnt     = (int*)(wsb + 159402768);                      // 400,000 B
    int* eidx    = (int*)(wsb + 159802768);                      // 800,000 B
    int* bsum    = (int*)(wsb + 160602768);                      // 2 KB
    float* alphag= (float*)(wsb + 160604816);                    // 3.2 MB

    // ---- CSR build ----
    zero_k<<<(NN + 255) / 256, 256, 0, stream>>>((unsigned*)cnt, NN);
    hist_k<<<(NNZ_C + 255) / 256, 256, 0, stream>>>(row, cnt);
    scan1_k<<<(NN + 255) / 256, 256, 0, stream>>>(cnt, rowptr, bsum, NN);
    scan2_k<<<1, 512, 0, stream>>>(bsum, (NN + 255) / 256);
    scan3_k<<<(NN + 255) / 256, 256, 0, stream>>>(rowptr, bsum, cnt, NN);
    fill_k<<<(NNZ_C + 255) / 256, 256, 0, stream>>>(row, cnt, eidx);

    // ---- weight prep ----
    wtr_k<true><<<256, 256, 0, stream>>>(Wlin, Wlp, 512);
    wtr_k<false><<<64, 256, 0, stream>>>(Wn, WnT, 128);
    wtr_k<false><<<64, 256, 0, stream>>>(We, WeT, 128);
    attw_k<<<1, 256, 0, stream>>>(Wlin, att, bn, be, A1, A2, bnbe);

    // ---- X pipeline: Xlin + ax in one pass over X (BM=64, R13-proven) ----
    gemmx_k<<<1563, 256, 0, stream>>>(X, Wlp, A1, Xlin, ax, NN);

    // ---- E path: agg -> combined GEMM -> ae ----
    agg_k<<<ENUM / 4, 256, 0, stream>>>(row, adjv, X, agg);
    gemme_k<<<391, 256, 0, stream>>>(agg, E, WnT, WeT, bnbe, Eres, ENUM);
    ae_k<<<ENUM / 4, 256, 0, stream>>>(Eres, A2, ae);

    // ---- CSR softmax (one thread per row) ----
    softmax_csr_k<<<(NN + 255) / 256, 256, 0, stream>>>(rowptr, eidx, ax, ae, alpha, alphag);

    // ---- node -> hyperedge ----
    out_e_k<<<ENUM / 4, 256, 0, stream>>>(row, alpha, Xlin, out_e);

    // ---- hyperedge -> node ----
    xgather_k<<<NN / 4, 256, 0, stream>>>(rowptr, eidx, adjv, alphag, out_e, bias_conv, Xres);
}